// Round 5
// baseline (232.736 us; speedup 1.0000x reference)
//
#include <hip/hip_runtime.h>
#include <hip/hip_bf16.h>

// Problem constants
#define B    2
#define CIN  256
#define H    56
#define W    56
#define OUTC 256
#define KS   7
#define PAD  3
#define G    8
#define CG   32
#define HP   62           // H + 2*PAD
#define WP   62
#define P1   (H * W)      // 3136
#define P2   (HP * WP)    // 3844

#define XPAD_N (B * CIN * P2)     // 1,968,128
#define WT_N   (OUTC * CIN)       // 65,536

// ---------------------------------------------------------------------------
// Prep: build zero-padded fm_t0 copy (xpad) and 3 transposed weights wT[k][o].
// ---------------------------------------------------------------------------
__global__ __launch_bounds__(256) void prep_kernel(const float* __restrict__ fm,
                                                   const float* __restrict__ wq,
                                                   const float* __restrict__ wk,
                                                   const float* __restrict__ wv,
                                                   float* __restrict__ xpad,
                                                   float* __restrict__ wtq,
                                                   float* __restrict__ wtk,
                                                   float* __restrict__ wtv) {
    const int total = XPAD_N + 3 * WT_N;
    for (int idx = blockIdx.x * 256 + threadIdx.x; idx < total; idx += gridDim.x * 256) {
        if (idx < XPAD_N) {
            const int pp = idx % P2;
            const int bc = idx / P2;           // b*256 + c
            const int yy = pp / WP, xx = pp - yy * WP;
            float v = 0.f;
            if (yy >= PAD && yy < PAD + H && xx >= PAD && xx < PAD + W) {
                const int b = bc >> 8, c = bc & 255;
                v = fm[((size_t)b * (2 * CIN) + c) * P1 + (yy - PAD) * W + (xx - PAD)];
            }
            xpad[idx] = v;
        } else {
            const int i2 = idx - XPAD_N;
            const int mat = i2 >> 16;          // 0,1,2
            const int r = i2 & 65535;
            const int o = r & 255, k = r >> 8;
            const float* src = (mat == 0) ? wq : (mat == 1) ? wk : wv;
            float* dst = (mat == 0) ? wtq : (mat == 1) ? wtk : wtv;
            dst[k * OUTC + o] = src[o * CIN + k];
        }
    }
}

// ---------------------------------------------------------------------------
// Streamed-X GEMM for q: block = 4 waves; wave w owns 4 output channels;
// each lane owns 8 pixels (two float4 halves). W read per k is wave-uniform.
// No LDS, no barriers. p-blocks of 512, last block clamped (overlap-write).
// ---------------------------------------------------------------------------
__global__ __launch_bounds__(256) void proj_q_kernel(const float* __restrict__ fm,
                                                     const float* __restrict__ wtq,
                                                     float* __restrict__ q) {
    const int b = blockIdx.z;
    const int tid = threadIdx.x;
    const int wave = __builtin_amdgcn_readfirstlane(tid >> 6);
    const int lane = tid & 63;
    const int o0 = blockIdx.y * 16 + wave * 4;
    int p0 = blockIdx.x * 512;
    if (p0 > P1 - 512) p0 = P1 - 512;          // clamp; overlapping writes are identical
    const int pA = p0 + 4 * lane;
    const int pB = pA + 256;

    const float* X = fm + ((size_t)b * (2 * CIN) + CIN) * P1;   // fm_t1[b]

    float accA[4][4] = {};
    float accB[4][4] = {};

    float4 xA = *(const float4*)&X[pA];
    float4 xB = *(const float4*)&X[pB];
    float4 w4 = *(const float4*)&wtq[o0];

    for (int k = 0; k < CIN; ++k) {
        float4 nxA, nxB, nw;
        if (k + 1 < CIN) {
            nxA = *(const float4*)&X[(size_t)(k + 1) * P1 + pA];
            nxB = *(const float4*)&X[(size_t)(k + 1) * P1 + pB];
            nw  = *(const float4*)&wtq[(k + 1) * OUTC + o0];
        }
        const float wr[4] = {w4.x, w4.y, w4.z, w4.w};
        const float xa[4] = {xA.x, xA.y, xA.z, xA.w};
        const float xb[4] = {xB.x, xB.y, xB.z, xB.w};
        #pragma unroll
        for (int oo = 0; oo < 4; ++oo)
            #pragma unroll
            for (int pp = 0; pp < 4; ++pp) {
                accA[oo][pp] += wr[oo] * xa[pp];
                accB[oo][pp] += wr[oo] * xb[pp];
            }
        xA = nxA; xB = nxB; w4 = nw;
    }
    float* qb = q + (size_t)b * OUTC * P1;
    #pragma unroll
    for (int oo = 0; oo < 4; ++oo) {
        *(float4*)&qb[(size_t)(o0 + oo) * P1 + pA] = make_float4(accA[oo][0], accA[oo][1], accA[oo][2], accA[oo][3]);
        *(float4*)&qb[(size_t)(o0 + oo) * P1 + pB] = make_float4(accB[oo][0], accB[oo][1], accB[oo][2], accB[oo][3]);
    }
}

// ---------------------------------------------------------------------------
// Streamed-X GEMM for k and v (shared X reads from xpad).
// ---------------------------------------------------------------------------
__global__ __launch_bounds__(256) void proj_kv_kernel(const float* __restrict__ xpad,
                                                      const float* __restrict__ wtk,
                                                      const float* __restrict__ wtv,
                                                      float* __restrict__ kk,
                                                      float* __restrict__ vv) {
    const int b = blockIdx.z;
    const int tid = threadIdx.x;
    const int wave = __builtin_amdgcn_readfirstlane(tid >> 6);
    const int lane = tid & 63;
    const int o0 = blockIdx.y * 16 + wave * 4;
    int p0 = blockIdx.x * 512;
    if (p0 > P2 - 512) p0 = P2 - 512;
    const int pA = p0 + 4 * lane;
    const int pB = pA + 256;

    const float* X = xpad + (size_t)b * CIN * P2;

    float akA[4][4] = {}, akB[4][4] = {};
    float avA[4][4] = {}, avB[4][4] = {};

    float4 xA = *(const float4*)&X[pA];
    float4 xB = *(const float4*)&X[pB];
    float4 wk4 = *(const float4*)&wtk[o0];
    float4 wv4 = *(const float4*)&wtv[o0];

    for (int k = 0; k < CIN; ++k) {
        float4 nxA, nxB, nwk, nwv;
        if (k + 1 < CIN) {
            nxA = *(const float4*)&X[(size_t)(k + 1) * P2 + pA];
            nxB = *(const float4*)&X[(size_t)(k + 1) * P2 + pB];
            nwk = *(const float4*)&wtk[(k + 1) * OUTC + o0];
            nwv = *(const float4*)&wtv[(k + 1) * OUTC + o0];
        }
        const float wkr[4] = {wk4.x, wk4.y, wk4.z, wk4.w};
        const float wvr[4] = {wv4.x, wv4.y, wv4.z, wv4.w};
        const float xa[4]  = {xA.x, xA.y, xA.z, xA.w};
        const float xb[4]  = {xB.x, xB.y, xB.z, xB.w};
        #pragma unroll
        for (int oo = 0; oo < 4; ++oo)
            #pragma unroll
            for (int pp = 0; pp < 4; ++pp) {
                akA[oo][pp] += wkr[oo] * xa[pp];
                akB[oo][pp] += wkr[oo] * xb[pp];
                avA[oo][pp] += wvr[oo] * xa[pp];
                avB[oo][pp] += wvr[oo] * xb[pp];
            }
        xA = nxA; xB = nxB; wk4 = nwk; wv4 = nwv;
    }
    float* kb = kk + (size_t)b * OUTC * P2;
    float* vb = vv + (size_t)b * OUTC * P2;
    #pragma unroll
    for (int oo = 0; oo < 4; ++oo) {
        const size_t row = (size_t)(o0 + oo);
        *(float4*)&kb[row * P2 + pA] = make_float4(akA[oo][0], akA[oo][1], akA[oo][2], akA[oo][3]);
        *(float4*)&kb[row * P2 + pB] = make_float4(akB[oo][0], akB[oo][1], akB[oo][2], akB[oo][3]);
        *(float4*)&vb[row * P2 + pA] = make_float4(avA[oo][0], avA[oo][1], avA[oo][2], avA[oo][3]);
        *(float4*)&vb[row * P2 + pB] = make_float4(avB[oo][0], avB[oo][1], avB[oo][2], avB[oo][3]);
    }
}

// ---------------------------------------------------------------------------
// Grouped 7x7 attention, channel-split pipelined staging.
// Block = 2 pixel rows x 56 cols for one (b,g): 128 threads, 112 active.
// Window = 8 padded rows x 62 cols = 496 positions; channels split in two
// halves of 16 (4 float4-subs each). bufA = subs 0-3, bufB = subs 4-7.
// Pipeline: K-A | QK-A + stage K-B | QK-B + stage V-A | PV-A + stage V-B | PV-B
// NOTE: global load index is (wroot + ch*P2)[pos]; pos already includes the
// lane offset sl — wroot must NOT add sl (R4 bug: double-counted sl).
// ---------------------------------------------------------------------------
#define NPOS 496          // 8 * 62
#define SSTRIDE 498       // padded sub stride (bank stagger)
__global__ __launch_bounds__(128) void attn_kernel(const float* __restrict__ q,
                                                   const float* __restrict__ kk,
                                                   const float* __restrict__ vv,
                                                   const float* __restrict__ rel_h,
                                                   const float* __restrict__ rel_w,
                                                   float* __restrict__ out) {
    __shared__ float4 sbuf[8 * SSTRIDE];   // 63,744 B -> 2 blocks/CU

    const int b  = blockIdx.z;
    const int g  = blockIdx.y;
    const int r0 = blockIdx.x * 2;
    const int oc0 = g * CG;
    const size_t boc = (size_t)b * OUTC + oc0;
    const int tid = threadIdx.x;
    const bool active = tid < 112;
    const int rr = tid / 56;
    const int cx = tid - rr * 56;
    const int pix = (r0 + rr) * W + cx;

    // staging map: sub = tid>>5 (0..3 within half), sl = tid&31, pos = sl + it*32
    const int ssub = tid >> 5;
    const int sl   = tid & 31;
    const size_t wroot = boc * P2 + (size_t)r0 * WP;   // lane offset lives in pos

    float4* bufA = sbuf;
    float4* bufB = sbuf + 4 * SSTRIDE;

    // q loads first (overlap K-A staging)
    float qv[8][4];
    if (active) {
        #pragma unroll
        for (int sub = 0; sub < 8; ++sub) {
            const float* qp = q + (boc + sub * 4) * P1 + pix;
            qv[sub][0] = qp[0];
            qv[sub][1] = qp[(size_t)P1];
            qv[sub][2] = qp[(size_t)2 * P1];
            qv[sub][3] = qp[(size_t)3 * P1];
        }
    }

    float4 st[16];
    // ---- load + write K half A (channels oc0 + ssub*4 ..) ----
    {
        const float* gp = kk + wroot + (size_t)(ssub * 4) * P2;
        #pragma unroll
        for (int it = 0; it < 16; ++it) {
            const int pos = sl + it * 32;
            if (pos < NPOS)
                st[it] = make_float4(gp[pos], gp[pos + (size_t)P2], gp[pos + (size_t)2 * P2], gp[pos + (size_t)3 * P2]);
        }
        #pragma unroll
        for (int it = 0; it < 16; ++it) {
            const int pos = sl + it * 32;
            if (pos < NPOS) bufA[ssub * SSTRIDE + pos] = st[it];
        }
    }
    __syncthreads();   // B1: K-A ready

    // issue K half B loads
    {
        const float* gp = kk + wroot + (size_t)(16 + ssub * 4) * P2;
        #pragma unroll
        for (int it = 0; it < 16; ++it) {
            const int pos = sl + it * 32;
            if (pos < NPOS)
                st[it] = make_float4(gp[pos], gp[pos + (size_t)P2], gp[pos + (size_t)2 * P2], gp[pos + (size_t)3 * P2]);
        }
    }

    float logits[KS * KS];
    if (active) {
        // bias init
        const float* rel = (g < 4) ? (rel_h + oc0 * KS) : (rel_w + (oc0 - 128) * KS);
        float biasdot[KS];
        #pragma unroll
        for (int t = 0; t < KS; ++t) {
            float s = 0.f;
            #pragma unroll
            for (int sub = 0; sub < 8; ++sub)
                #pragma unroll
                for (int j = 0; j < 4; ++j)
                    s += qv[sub][j] * rel[(sub * 4 + j) * KS + t];
            biasdot[t] = s;
        }
        #pragma unroll
        for (int i = 0; i < KS; ++i)
            #pragma unroll
            for (int j = 0; j < KS; ++j)
                logits[i * KS + j] = (g < 4) ? biasdot[i] : biasdot[j];

        // QK half A (subs 0-3)
        #pragma unroll
        for (int sub = 0; sub < 4; ++sub) {
            const float qx = qv[sub][0], qy = qv[sub][1], qz = qv[sub][2], qw = qv[sub][3];
            #pragma unroll
            for (int i = 0; i < KS; ++i) {
                const int rowoff = sub * SSTRIDE + (rr + i) * WP + cx;
                #pragma unroll
                for (int j = 0; j < KS; ++j) {
                    const float4 kv4 = bufA[rowoff + j];
                    logits[i * KS + j] += qx * kv4.x + qy * kv4.y + qz * kv4.z + qw * kv4.w;
                }
            }
        }
    }
    // write K half B
    #pragma unroll
    for (int it = 0; it < 16; ++it) {
        const int pos = sl + it * 32;
        if (pos < NPOS) bufB[ssub * SSTRIDE + pos] = st[it];
    }
    __syncthreads();   // B2: K-B ready, QK-A done everywhere

    // issue V half A loads
    {
        const float* gp = vv + wroot + (size_t)(ssub * 4) * P2;
        #pragma unroll
        for (int it = 0; it < 16; ++it) {
            const int pos = sl + it * 32;
            if (pos < NPOS)
                st[it] = make_float4(gp[pos], gp[pos + (size_t)P2], gp[pos + (size_t)2 * P2], gp[pos + (size_t)3 * P2]);
        }
    }

    if (active) {
        // QK half B (subs 4-7 -> bufB local subs 0-3)
        #pragma unroll
        for (int sub = 0; sub < 4; ++sub) {
            const float qx = qv[4 + sub][0], qy = qv[4 + sub][1], qz = qv[4 + sub][2], qw = qv[4 + sub][3];
            #pragma unroll
            for (int i = 0; i < KS; ++i) {
                const int rowoff = sub * SSTRIDE + (rr + i) * WP + cx;
                #pragma unroll
                for (int j = 0; j < KS; ++j) {
                    const float4 kv4 = bufB[rowoff + j];
                    logits[i * KS + j] += qx * kv4.x + qy * kv4.y + qz * kv4.z + qw * kv4.w;
                }
            }
        }
        // softmax
        float m = logits[0];
        #pragma unroll
        for (int t = 1; t < KS * KS; ++t) m = fmaxf(m, logits[t]);
        float sum = 0.f;
        #pragma unroll
        for (int t = 0; t < KS * KS; ++t) {
            const float e = __expf(logits[t] - m);
            logits[t] = e;
            sum += e;
        }
        const float inv = 1.f / sum;
        #pragma unroll
        for (int t = 0; t < KS * KS; ++t) logits[t] *= inv;
    }
    // write V half A
    #pragma unroll
    for (int it = 0; it < 16; ++it) {
        const int pos = sl + it * 32;
        if (pos < NPOS) bufA[ssub * SSTRIDE + pos] = st[it];
    }
    __syncthreads();   // B3: V-A ready, QK-B done everywhere

    // issue V half B loads
    {
        const float* gp = vv + wroot + (size_t)(16 + ssub * 4) * P2;
        #pragma unroll
        for (int it = 0; it < 16; ++it) {
            const int pos = sl + it * 32;
            if (pos < NPOS)
                st[it] = make_float4(gp[pos], gp[pos + (size_t)P2], gp[pos + (size_t)2 * P2], gp[pos + (size_t)3 * P2]);
        }
    }

    if (active) {
        // PV half A (subs 0-3)
        #pragma unroll
        for (int sub = 0; sub < 4; ++sub) {
            float ax = 0.f, ay = 0.f, az = 0.f, aw = 0.f;
            #pragma unroll
            for (int i = 0; i < KS; ++i) {
                const int rowoff = sub * SSTRIDE + (rr + i) * WP + cx;
                #pragma unroll
                for (int j = 0; j < KS; ++j) {
                    const float4 v4 = bufA[rowoff + j];
                    const float wt = logits[i * KS + j];
                    ax += wt * v4.x; ay += wt * v4.y; az += wt * v4.z; aw += wt * v4.w;
                }
            }
            float* op = out + (boc + sub * 4) * P1 + pix;
            op[0] = ax; op[(size_t)P1] = ay; op[(size_t)2 * P1] = az; op[(size_t)3 * P1] = aw;
        }
    }
    // write V half B
    #pragma unroll
    for (int it = 0; it < 16; ++it) {
        const int pos = sl + it * 32;
        if (pos < NPOS) bufB[ssub * SSTRIDE + pos] = st[it];
    }
    __syncthreads();   // B4: V-B ready, PV-A done everywhere

    if (active) {
        // PV half B (subs 4-7)
        #pragma unroll
        for (int sub = 0; sub < 4; ++sub) {
            float ax = 0.f, ay = 0.f, az = 0.f, aw = 0.f;
            #pragma unroll
            for (int i = 0; i < KS; ++i) {
                const int rowoff = sub * SSTRIDE + (rr + i) * WP + cx;
                #pragma unroll
                for (int j = 0; j < KS; ++j) {
                    const float4 v4 = bufB[rowoff + j];
                    const float wt = logits[i * KS + j];
                    ax += wt * v4.x; ay += wt * v4.y; az += wt * v4.z; aw += wt * v4.w;
                }
            }
            float* op = out + (boc + (4 + sub) * 4) * P1 + pix;
            op[0] = ax; op[(size_t)P1] = ay; op[(size_t)2 * P1] = az; op[(size_t)3 * P1] = aw;
        }
    }
}

extern "C" void kernel_launch(void* const* d_in, const int* in_sizes, int n_in,
                              void* d_out, int out_size, void* d_ws, size_t ws_size,
                              hipStream_t stream) {
    const float* fm = (const float*)d_in[0];
    const float* wq = (const float*)d_in[1];
    const float* wk = (const float*)d_in[2];
    const float* wv = (const float*)d_in[3];
    const float* rh = (const float*)d_in[4];
    const float* rw = (const float*)d_in[5];
    float* out = (float*)d_out;

    float* ws   = (float*)d_ws;
    float* q    = ws;                                   // B*OUTC*P1
    float* kk   = q + (size_t)B * OUTC * P1;            // B*OUTC*P2
    float* vv   = kk + (size_t)B * OUTC * P2;           // B*OUTC*P2
    float* xpad = vv + (size_t)B * OUTC * P2;           // B*CIN*P2
    float* wtq  = xpad + (size_t)XPAD_N;                // 256*256
    float* wtk  = wtq + WT_N;
    float* wtv  = wtk + WT_N;

    prep_kernel<<<1024, 256, 0, stream>>>(fm, wq, wk, wv, xpad, wtq, wtk, wtv);
    proj_q_kernel<<<dim3(7, OUTC / 16, B), 256, 0, stream>>>(fm, wtq, q);
    proj_kv_kernel<<<dim3(8, OUTC / 16, B), 256, 0, stream>>>(xpad, wtk, wtv, kk, vv);
    attn_kernel<<<dim3(H / 2, G, B), 128, 0, stream>>>(q, kk, vv, rh, rw, out);
}

// Round 7
// 158.257 us; speedup vs baseline: 1.4706x; 1.4706x over previous
//
#include <hip/hip_runtime.h>
#include <hip/hip_bf16.h>

// Problem constants
#define B    2
#define CIN  256
#define H    56
#define W    56
#define OUTC 256
#define KS   7
#define PAD  3
#define G    8
#define CG   32
#define HP   62           // H + 2*PAD
#define WP   62
#define P1   (H * W)      // 3136
#define P2   (HP * WP)    // 3844

#define N1PAD 3200        // 25 * 128 (q-side padded pixel rows)
#define N0PAD 3968        // 31 * 128 (kv-side padded pixel rows)

typedef __attribute__((ext_vector_type(8))) _Float16 f16x8;
typedef __attribute__((ext_vector_type(8))) unsigned short ushort8;
typedef __attribute__((ext_vector_type(4))) float f32x4;

__device__ inline unsigned short f2h(float f) {    // RNE float->fp16 bits
    const _Float16 h = (_Float16)f;
    return *(const unsigned short*)&h;
}

// ---------------------------------------------------------------------------
// prep_w: wq -> wqb[256][256] fp16 ; wk,wv -> wkvb[512][256] fp16 (stacked)
// ---------------------------------------------------------------------------
__global__ __launch_bounds__(256) void prep_w_kernel(const float* __restrict__ wq,
                                                     const float* __restrict__ wk,
                                                     const float* __restrict__ wv,
                                                     unsigned short* __restrict__ wqb,
                                                     unsigned short* __restrict__ wkvb) {
    const int e = (blockIdx.x * 256 + threadIdx.x) * 4;     // 0..196604
    const float* s;
    unsigned short* d;
    if (e < 65536)       { s = wq + e;            d = wqb + e; }
    else if (e < 131072) { s = wk + (e - 65536);  d = wkvb + (e - 65536); }
    else                 { s = wv + (e - 131072); d = wkvb + (e - 65536); }
    const float4 v = *(const float4*)s;
    ushort4 t;
    t.x = f2h(v.x); t.y = f2h(v.y); t.z = f2h(v.z); t.w = f2h(v.w);
    *(ushort4*)d = t;
}

// ---------------------------------------------------------------------------
// prep_x1: Xt1[b][p][c] fp16, p < N1PAD (zeros for p >= P1). Source fm_t1.
// ---------------------------------------------------------------------------
__global__ __launch_bounds__(256) void prep_x1_kernel(const float* __restrict__ fm,
                                                      unsigned short* __restrict__ xt1) {
    const int b  = blockIdx.z;
    const int c0 = blockIdx.y * 64;
    const int p  = blockIdx.x * 256 + threadIdx.x;
    if (p >= N1PAD) return;
    const bool valid = p < P1;
    const float* src = fm + ((size_t)b * (2 * CIN) + CIN + c0) * P1 + p;
    unsigned short* dst = xt1 + ((size_t)b * N1PAD + p) * CIN + c0;
    #pragma unroll
    for (int c8 = 0; c8 < 8; ++c8) {
        ushort8 t;
        #pragma unroll
        for (int j = 0; j < 8; ++j) {
            const float v = valid ? src[(size_t)(c8 * 8 + j) * P1] : 0.f;
            t[j] = f2h(v);
        }
        *(ushort8*)(dst + c8 * 8) = t;
    }
}

// ---------------------------------------------------------------------------
// prep_x0: Xt0[b][pp][c] fp16, pp indexes the PADDED 62x62 plane (zeros
// outside the valid interior and for pp >= P2). Source fm_t0.
// ---------------------------------------------------------------------------
__global__ __launch_bounds__(256) void prep_x0_kernel(const float* __restrict__ fm,
                                                      unsigned short* __restrict__ xt0) {
    const int b  = blockIdx.z;
    const int c0 = blockIdx.y * 64;
    const int pp = blockIdx.x * 256 + threadIdx.x;
    if (pp >= N0PAD) return;
    int srcoff = -1;
    if (pp < P2) {
        const int y = pp / WP, x = pp - y * WP;
        const int iy = y - PAD, ix = x - PAD;
        if (iy >= 0 && iy < H && ix >= 0 && ix < W) srcoff = iy * W + ix;
    }
    const float* src = fm + ((size_t)b * (2 * CIN) + c0) * P1;
    unsigned short* dst = xt0 + ((size_t)b * N0PAD + pp) * CIN + c0;
    #pragma unroll
    for (int c8 = 0; c8 < 8; ++c8) {
        ushort8 t;
        #pragma unroll
        for (int j = 0; j < 8; ++j) {
            const float v = (srcoff >= 0) ? src[(size_t)(c8 * 8 + j) * P1 + srcoff] : 0.f;
            t[j] = f2h(v);
        }
        *(ushort8*)(dst + c8 * 8) = t;
    }
}

// ---------------------------------------------------------------------------
// fp16 MFMA GEMM: out[m][n] = sum_k Wb[m][k] * Xt[n][k]   (gemm_bt pattern)
// 128x128 tile, 256 thr (4 waves = 64x64 quadrants of 4x4 16x16 tiles),
// BK=32, register-prefetched staging, LDS stride 40.
// Output fp32 planes: rows < 256 -> out_lo, rows >= 256 -> out_hi (kv stack).
// ---------------------------------------------------------------------------
#define ASTR 40
__global__ __launch_bounds__(256, 2) void gemm_kernel(const unsigned short* __restrict__ Wb,
                                                      const unsigned short* __restrict__ Xt,
                                                      float* __restrict__ out_lo,
                                                      float* __restrict__ out_hi,
                                                      int Nreal, int NPAD, int outPstride) {
    __shared__ unsigned short Alds[128 * ASTR];
    __shared__ unsigned short Blds[128 * ASTR];
    const int b   = blockIdx.z;
    const int o0  = blockIdx.y * 128;
    const int n0  = blockIdx.x * 128;
    const int tid = threadIdx.x;
    const int lane = tid & 63;
    const int wave = tid >> 6;
    const int wr = (wave >> 1) * 64;    // m offset of wave quadrant
    const int wc = (wave & 1) * 64;     // n offset
    const int lrow = lane & 15;
    const int quad = lane >> 4;

    const unsigned short* Ag = Wb + (size_t)o0 * CIN;
    const unsigned short* Bg = Xt + ((size_t)b * NPAD + n0) * CIN;

    // staging map: thread -> row (0..127) and 16-elem k-chunk (0 or 16)
    const int arow = tid >> 1;
    const int akc  = (tid & 1) * 16;
    const unsigned short* agp = Ag + (size_t)arow * CIN + akc;
    const unsigned short* bgp = Bg + (size_t)arow * CIN + akc;
    unsigned short* alp = Alds + arow * ASTR + akc;
    unsigned short* blp = Blds + arow * ASTR + akc;

    f32x4 acc[4][4] = {};

    f16x8 pa0 = *(const f16x8*)(agp);
    f16x8 pa1 = *(const f16x8*)(agp + 8);
    f16x8 pb0 = *(const f16x8*)(bgp);
    f16x8 pb1 = *(const f16x8*)(bgp + 8);

    for (int kb = 0; kb < CIN / 32; ++kb) {
        *(f16x8*)(alp)     = pa0;
        *(f16x8*)(alp + 8) = pa1;
        *(f16x8*)(blp)     = pb0;
        *(f16x8*)(blp + 8) = pb1;
        __syncthreads();
        if (kb < CIN / 32 - 1) {          // prefetch next K-block (drains under MFMA)
            const int ko = (kb + 1) * 32;
            pa0 = *(const f16x8*)(agp + ko);
            pa1 = *(const f16x8*)(agp + ko + 8);
            pb0 = *(const f16x8*)(bgp + ko);
            pb1 = *(const f16x8*)(bgp + ko + 8);
        }
        f16x8 af[4], bfr[4];
        #pragma unroll
        for (int mi = 0; mi < 4; ++mi)
            af[mi] = *(const f16x8*)&Alds[(wr + mi * 16 + lrow) * ASTR + quad * 8];
        #pragma unroll
        for (int ni = 0; ni < 4; ++ni)
            bfr[ni] = *(const f16x8*)&Blds[(wc + ni * 16 + lrow) * ASTR + quad * 8];
        #pragma unroll
        for (int mi = 0; mi < 4; ++mi)
            #pragma unroll
            for (int ni = 0; ni < 4; ++ni)
                acc[mi][ni] = __builtin_amdgcn_mfma_f32_16x16x32_f16(af[mi], bfr[ni], acc[mi][ni], 0, 0, 0);
        __syncthreads();
    }

    // epilogue: C/D layout col=lane&15, row=quad*4+reg (dtype-independent)
    #pragma unroll
    for (int mi = 0; mi < 4; ++mi) {
        const int gmBase = o0 + wr + mi * 16 + quad * 4;
        #pragma unroll
        for (int ni = 0; ni < 4; ++ni) {
            const int gn = n0 + wc + ni * 16 + lrow;
            if (gn < Nreal) {
                #pragma unroll
                for (int r = 0; r < 4; ++r) {
                    const int gm = gmBase + r;
                    float* dst = (gm < 256)
                        ? out_lo + ((size_t)b * 256 + gm) * outPstride + gn
                        : out_hi + ((size_t)b * 256 + (gm - 256)) * outPstride + gn;
                    *dst = acc[mi][ni][r];
                }
            }
        }
    }
}

// ---------------------------------------------------------------------------
// Grouped 7x7 attention, channel-split pipelined staging (unchanged, passing).
// ---------------------------------------------------------------------------
#define NPOS 496          // 8 * 62
#define SSTRIDE 498       // padded sub stride
__global__ __launch_bounds__(128) void attn_kernel(const float* __restrict__ q,
                                                   const float* __restrict__ kk,
                                                   const float* __restrict__ vv,
                                                   const float* __restrict__ rel_h,
                                                   const float* __restrict__ rel_w,
                                                   float* __restrict__ out) {
    __shared__ float4 sbuf[8 * SSTRIDE];

    const int b  = blockIdx.z;
    const int g  = blockIdx.y;
    const int r0 = blockIdx.x * 2;
    const int oc0 = g * CG;
    const size_t boc = (size_t)b * OUTC + oc0;
    const int tid = threadIdx.x;
    const bool active = tid < 112;
    const int rr = tid / 56;
    const int cx = tid - rr * 56;
    const int pix = (r0 + rr) * W + cx;

    const int ssub = tid >> 5;
    const int sl   = tid & 31;
    const size_t wroot = boc * P2 + (size_t)r0 * WP;   // lane offset lives in pos

    float4* bufA = sbuf;
    float4* bufB = sbuf + 4 * SSTRIDE;

    float qv[8][4];
    if (active) {
        #pragma unroll
        for (int sub = 0; sub < 8; ++sub) {
            const float* qp = q + (boc + sub * 4) * P1 + pix;
            qv[sub][0] = qp[0];
            qv[sub][1] = qp[(size_t)P1];
            qv[sub][2] = qp[(size_t)2 * P1];
            qv[sub][3] = qp[(size_t)3 * P1];
        }
    }

    float4 st[16];
    {
        const float* gp = kk + wroot + (size_t)(ssub * 4) * P2;
        #pragma unroll
        for (int it = 0; it < 16; ++it) {
            const int pos = sl + it * 32;
            if (pos < NPOS)
                st[it] = make_float4(gp[pos], gp[pos + (size_t)P2], gp[pos + (size_t)2 * P2], gp[pos + (size_t)3 * P2]);
        }
        #pragma unroll
        for (int it = 0; it < 16; ++it) {
            const int pos = sl + it * 32;
            if (pos < NPOS) bufA[ssub * SSTRIDE + pos] = st[it];
        }
    }
    __syncthreads();   // B1: K-A ready

    {
        const float* gp = kk + wroot + (size_t)(16 + ssub * 4) * P2;
        #pragma unroll
        for (int it = 0; it < 16; ++it) {
            const int pos = sl + it * 32;
            if (pos < NPOS)
                st[it] = make_float4(gp[pos], gp[pos + (size_t)P2], gp[pos + (size_t)2 * P2], gp[pos + (size_t)3 * P2]);
        }
    }

    float logits[KS * KS];
    if (active) {
        const float* rel = (g < 4) ? (rel_h + oc0 * KS) : (rel_w + (oc0 - 128) * KS);
        float biasdot[KS];
        #pragma unroll
        for (int t = 0; t < KS; ++t) {
            float s = 0.f;
            #pragma unroll
            for (int sub = 0; sub < 8; ++sub)
                #pragma unroll
                for (int j = 0; j < 4; ++j)
                    s += qv[sub][j] * rel[(sub * 4 + j) * KS + t];
            biasdot[t] = s;
        }
        #pragma unroll
        for (int i = 0; i < KS; ++i)
            #pragma unroll
            for (int j = 0; j < KS; ++j)
                logits[i * KS + j] = (g < 4) ? biasdot[i] : biasdot[j];

        #pragma unroll
        for (int sub = 0; sub < 4; ++sub) {
            const float qx = qv[sub][0], qy = qv[sub][1], qz = qv[sub][2], qw = qv[sub][3];
            #pragma unroll
            for (int i = 0; i < KS; ++i) {
                const int rowoff = sub * SSTRIDE + (rr + i) * WP + cx;
                #pragma unroll
                for (int j = 0; j < KS; ++j) {
                    const float4 kv4 = bufA[rowoff + j];
                    logits[i * KS + j] += qx * kv4.x + qy * kv4.y + qz * kv4.z + qw * kv4.w;
                }
            }
        }
    }
    #pragma unroll
    for (int it = 0; it < 16; ++it) {
        const int pos = sl + it * 32;
        if (pos < NPOS) bufB[ssub * SSTRIDE + pos] = st[it];
    }
    __syncthreads();   // B2

    {
        const float* gp = vv + wroot + (size_t)(ssub * 4) * P2;
        #pragma unroll
        for (int it = 0; it < 16; ++it) {
            const int pos = sl + it * 32;
            if (pos < NPOS)
                st[it] = make_float4(gp[pos], gp[pos + (size_t)P2], gp[pos + (size_t)2 * P2], gp[pos + (size_t)3 * P2]);
        }
    }

    if (active) {
        #pragma unroll
        for (int sub = 0; sub < 4; ++sub) {
            const float qx = qv[4 + sub][0], qy = qv[4 + sub][1], qz = qv[4 + sub][2], qw = qv[4 + sub][3];
            #pragma unroll
            for (int i = 0; i < KS; ++i) {
                const int rowoff = sub * SSTRIDE + (rr + i) * WP + cx;
                #pragma unroll
                for (int j = 0; j < KS; ++j) {
                    const float4 kv4 = bufB[rowoff + j];
                    logits[i * KS + j] += qx * kv4.x + qy * kv4.y + qz * kv4.z + qw * kv4.w;
                }
            }
        }
        float m = logits[0];
        #pragma unroll
        for (int t = 1; t < KS * KS; ++t) m = fmaxf(m, logits[t]);
        float sum = 0.f;
        #pragma unroll
        for (int t = 0; t < KS * KS; ++t) {
            const float e = __expf(logits[t] - m);
            logits[t] = e;
            sum += e;
        }
        const float inv = 1.f / sum;
        #pragma unroll
        for (int t = 0; t < KS * KS; ++t) logits[t] *= inv;
    }
    #pragma unroll
    for (int it = 0; it < 16; ++it) {
        const int pos = sl + it * 32;
        if (pos < NPOS) bufA[ssub * SSTRIDE + pos] = st[it];
    }
    __syncthreads();   // B3

    {
        const float* gp = vv + wroot + (size_t)(16 + ssub * 4) * P2;
        #pragma unroll
        for (int it = 0; it < 16; ++it) {
            const int pos = sl + it * 32;
            if (pos < NPOS)
                st[it] = make_float4(gp[pos], gp[pos + (size_t)P2], gp[pos + (size_t)2 * P2], gp[pos + (size_t)3 * P2]);
        }
    }

    if (active) {
        #pragma unroll
        for (int sub = 0; sub < 4; ++sub) {
            float ax = 0.f, ay = 0.f, az = 0.f, aw = 0.f;
            #pragma unroll
            for (int i = 0; i < KS; ++i) {
                const int rowoff = sub * SSTRIDE + (rr + i) * WP + cx;
                #pragma unroll
                for (int j = 0; j < KS; ++j) {
                    const float4 v4 = bufA[rowoff + j];
                    const float wt = logits[i * KS + j];
                    ax += wt * v4.x; ay += wt * v4.y; az += wt * v4.z; aw += wt * v4.w;
                }
            }
            float* op = out + (boc + sub * 4) * P1 + pix;
            op[0] = ax; op[(size_t)P1] = ay; op[(size_t)2 * P1] = az; op[(size_t)3 * P1] = aw;
        }
    }
    #pragma unroll
    for (int it = 0; it < 16; ++it) {
        const int pos = sl + it * 32;
        if (pos < NPOS) bufB[ssub * SSTRIDE + pos] = st[it];
    }
    __syncthreads();   // B4

    if (active) {
        #pragma unroll
        for (int sub = 0; sub < 4; ++sub) {
            float ax = 0.f, ay = 0.f, az = 0.f, aw = 0.f;
            #pragma unroll
            for (int i = 0; i < KS; ++i) {
                const int rowoff = sub * SSTRIDE + (rr + i) * WP + cx;
                #pragma unroll
                for (int j = 0; j < KS; ++j) {
                    const float4 v4 = bufB[rowoff + j];
                    const float wt = logits[i * KS + j];
                    ax += wt * v4.x; ay += wt * v4.y; az += wt * v4.z; aw += wt * v4.w;
                }
            }
            float* op = out + (boc + (4 + sub) * 4) * P1 + pix;
            op[0] = ax; op[(size_t)P1] = ay; op[(size_t)2 * P1] = az; op[(size_t)3 * P1] = aw;
        }
    }
}

extern "C" void kernel_launch(void* const* d_in, const int* in_sizes, int n_in,
                              void* d_out, int out_size, void* d_ws, size_t ws_size,
                              hipStream_t stream) {
    const float* fm = (const float*)d_in[0];
    const float* wq = (const float*)d_in[1];
    const float* wk = (const float*)d_in[2];
    const float* wv = (const float*)d_in[3];
    const float* rh = (const float*)d_in[4];
    const float* rw = (const float*)d_in[5];
    float* out = (float*)d_out;

    float* ws = (float*)d_ws;
    float* q  = ws;                                     // 2*256*3136 fp32
    float* kk = q + (size_t)B * OUTC * P1;              // 2*256*3844 fp32
    float* vv = kk + (size_t)B * OUTC * P2;             // 2*256*3844 fp32
    unsigned short* xt1  = (unsigned short*)(vv + (size_t)B * OUTC * P2);  // 2*3200*256 fp16
    unsigned short* xt0  = xt1 + (size_t)B * N1PAD * CIN;                  // 2*3968*256 fp16
    unsigned short* wqb  = xt0 + (size_t)B * N0PAD * CIN;                  // 256*256 fp16
    unsigned short* wkvb = wqb + OUTC * CIN;                               // 512*256 fp16

    prep_w_kernel<<<192, 256, 0, stream>>>(wq, wk, wv, wqb, wkvb);
    prep_x1_kernel<<<dim3(13, 4, B), 256, 0, stream>>>(fm, xt1);
    prep_x0_kernel<<<dim3(16, 4, B), 256, 0, stream>>>(fm, xt0);
    gemm_kernel<<<dim3(N1PAD / 128, 2, B), 256, 0, stream>>>(wqb, xt1, q, q, P1, N1PAD, P1);
    gemm_kernel<<<dim3(N0PAD / 128, 4, B), 256, 0, stream>>>(wkvb, xt0, kk, vv, P2, N0PAD, P2);
    attn_kernel<<<dim3(H / 2, G, B), 128, 0, stream>>>(q, kk, vv, rh, rw, out);
}

// Round 8
// 112.049 us; speedup vs baseline: 2.0771x; 1.4124x over previous
//
#include <hip/hip_runtime.h>
#include <hip/hip_bf16.h>

// Problem constants
#define B    2
#define CIN  256
#define H    56
#define W    56
#define OUTC 256
#define KS   7
#define PAD  3
#define G    8
#define CG   32
#define HP   62           // H + 2*PAD
#define WP   62
#define P1   (H * W)      // 3136
#define P2   (HP * WP)    // 3844

#define N1PAD 3200        // 25 * 128 (q-side padded pixel rows)
#define N0PAD 3968        // 31 * 128 (kv-side padded pixel rows)

typedef __attribute__((ext_vector_type(2))) _Float16 h2;
typedef __attribute__((ext_vector_type(8))) _Float16 f16x8;
typedef __attribute__((ext_vector_type(8))) unsigned short ushort8;
typedef __attribute__((ext_vector_type(4))) float f32x4;

__device__ inline unsigned short f2h(float f) {    // RNE float->fp16 bits
    const _Float16 h = (_Float16)f;
    return *(const unsigned short*)&h;
}

__device__ inline float fdot2(h2 a, h2 b, float c) {
#if defined(__has_builtin)
#if __has_builtin(__builtin_amdgcn_fdot2)
    return __builtin_amdgcn_fdot2(a, b, c, false);
#else
    return c + (float)a[0] * (float)b[0] + (float)a[1] * (float)b[1];
#endif
#else
    return c + (float)a[0] * (float)b[0] + (float)a[1] * (float)b[1];
#endif
}

// ---------------------------------------------------------------------------
// Fused prep (one launch): xt1[b][p][c] fp16 (q-side, zero-pad p>=P1),
// xt0[b][pp][c] fp16 (kv-side, padded 62x62 plane), wqb[256][256],
// wkvb[512][256] fp16. One 8-channel unit per thread; grid covers all units.
//   units: xt1 = 2*32*3200 = 204800 ; xt0 = 2*32*3968 = 253952 ; w = 24576
//   total 483328 = 1888 * 256
// ---------------------------------------------------------------------------
__global__ __launch_bounds__(256) void prep_kernel(const float* __restrict__ fm,
                                                   const float* __restrict__ wq,
                                                   const float* __restrict__ wk,
                                                   const float* __restrict__ wv,
                                                   unsigned short* __restrict__ xt1,
                                                   unsigned short* __restrict__ xt0,
                                                   unsigned short* __restrict__ wqb,
                                                   unsigned short* __restrict__ wkvb) {
    const int u = blockIdx.x * 256 + threadIdx.x;
    if (u < 204800) {                        // xt1: (b, c8, p), p fastest
        const int p  = u % 3200;
        const int t  = u / 3200;
        const int c8 = t & 31;
        const int b  = t >> 5;
        ushort8 o = {};
        if (p < P1) {
            const float* src = fm + ((size_t)(b * 512 + 256 + c8 * 8)) * P1 + p;
            #pragma unroll
            for (int j = 0; j < 8; ++j) o[j] = f2h(src[(size_t)j * P1]);
        }
        *(ushort8*)(xt1 + ((size_t)b * N1PAD + p) * CIN + c8 * 8) = o;
    } else if (u < 458752) {                 // xt0: (b, c8, pp)
        const int u2 = u - 204800;
        const int pp = u2 % 3968;
        const int t  = u2 / 3968;
        const int c8 = t & 31;
        const int b  = t >> 5;
        int srcoff = -1;
        if (pp < P2) {
            const int y = pp / WP, x = pp - y * WP;
            const int iy = y - PAD, ix = x - PAD;
            if (iy >= 0 && iy < H && ix >= 0 && ix < W) srcoff = iy * W + ix;
        }
        ushort8 o = {};
        if (srcoff >= 0) {
            const float* src = fm + ((size_t)(b * 512 + c8 * 8)) * P1 + srcoff;
            #pragma unroll
            for (int j = 0; j < 8; ++j) o[j] = f2h(src[(size_t)j * P1]);
        }
        *(ushort8*)(xt0 + ((size_t)b * N0PAD + pp) * CIN + c8 * 8) = o;
    } else {                                 // weights (stacked wq | wk | wv)
        const int e = (u - 458752) * 8;
        const float* s;
        unsigned short* d;
        if (e < 65536)       { s = wq + e;            d = wqb + e; }
        else if (e < 131072) { s = wk + (e - 65536);  d = wkvb + (e - 65536); }
        else                 { s = wv + (e - 131072); d = wkvb + (e - 65536); }
        const float4 v0 = ((const float4*)s)[0];
        const float4 v1 = ((const float4*)s)[1];
        ushort8 o;
        o[0] = f2h(v0.x); o[1] = f2h(v0.y); o[2] = f2h(v0.z); o[3] = f2h(v0.w);
        o[4] = f2h(v1.x); o[5] = f2h(v1.y); o[6] = f2h(v1.z); o[7] = f2h(v1.w);
        *(ushort8*)d = o;
    }
}

// ---------------------------------------------------------------------------
// Fused fp16 MFMA GEMM (one launch): grid (31, 6, B).
//   y<2  : q GEMM  (wqb 256 rows x xt1), x<25 only
//   y>=2 : kv GEMM (wkvb 512 rows x xt0)
// 128x128 tile, 4 waves, BK=32, register-prefetched staging, LDS stride 40.
// Epilogue writes fp16 INTERLEAVED planes: base[((b*8+g)*4+sub)*Pstr + n]*8+l8
// where ch = g*32 + sub*8 + l8. q rows -> qi ; kv rows <256 -> ki else vi.
// ---------------------------------------------------------------------------
#define ASTR 40
__global__ __launch_bounds__(256, 2) void gemm_kernel(const unsigned short* __restrict__ wqb,
                                                      const unsigned short* __restrict__ wkvb,
                                                      const unsigned short* __restrict__ xt1,
                                                      const unsigned short* __restrict__ xt0,
                                                      unsigned short* __restrict__ qi,
                                                      unsigned short* __restrict__ ki,
                                                      unsigned short* __restrict__ vi) {
    const int b = blockIdx.z;
    const bool isQ = blockIdx.y < 2;
    if (isQ && blockIdx.x >= 25) return;
    const int o0 = (isQ ? blockIdx.y : (blockIdx.y - 2)) * 128;
    const int n0 = blockIdx.x * 128;
    const unsigned short* Wb = isQ ? wqb : wkvb;
    const unsigned short* XtB = isQ ? (xt1 + (size_t)b * N1PAD * CIN)
                                    : (xt0 + (size_t)b * N0PAD * CIN);
    const int Nreal = isQ ? P1 : P2;
    const int Pstr  = isQ ? P1 : P2;

    __shared__ unsigned short Alds[128 * ASTR];
    __shared__ unsigned short Blds[128 * ASTR];
    const int tid = threadIdx.x;
    const int lane = tid & 63;
    const int wave = tid >> 6;
    const int wr = (wave >> 1) * 64;
    const int wc = (wave & 1) * 64;
    const int lrow = lane & 15;
    const int quad = lane >> 4;

    const unsigned short* Ag = Wb + (size_t)o0 * CIN;
    const unsigned short* Bg = XtB + (size_t)n0 * CIN;

    const int arow = tid >> 1;
    const int akc  = (tid & 1) * 16;
    const unsigned short* agp = Ag + (size_t)arow * CIN + akc;
    const unsigned short* bgp = Bg + (size_t)arow * CIN + akc;
    unsigned short* alp = Alds + arow * ASTR + akc;
    unsigned short* blp = Blds + arow * ASTR + akc;

    f32x4 acc[4][4] = {};

    f16x8 pa0 = *(const f16x8*)(agp);
    f16x8 pa1 = *(const f16x8*)(agp + 8);
    f16x8 pb0 = *(const f16x8*)(bgp);
    f16x8 pb1 = *(const f16x8*)(bgp + 8);

    for (int kb = 0; kb < CIN / 32; ++kb) {
        *(f16x8*)(alp)     = pa0;
        *(f16x8*)(alp + 8) = pa1;
        *(f16x8*)(blp)     = pb0;
        *(f16x8*)(blp + 8) = pb1;
        __syncthreads();
        if (kb < CIN / 32 - 1) {
            const int ko = (kb + 1) * 32;
            pa0 = *(const f16x8*)(agp + ko);
            pa1 = *(const f16x8*)(agp + ko + 8);
            pb0 = *(const f16x8*)(bgp + ko);
            pb1 = *(const f16x8*)(bgp + ko + 8);
        }
        f16x8 af[4], bfr[4];
        #pragma unroll
        for (int mi = 0; mi < 4; ++mi)
            af[mi] = *(const f16x8*)&Alds[(wr + mi * 16 + lrow) * ASTR + quad * 8];
        #pragma unroll
        for (int ni = 0; ni < 4; ++ni)
            bfr[ni] = *(const f16x8*)&Blds[(wc + ni * 16 + lrow) * ASTR + quad * 8];
        #pragma unroll
        for (int mi = 0; mi < 4; ++mi)
            #pragma unroll
            for (int ni = 0; ni < 4; ++ni)
                acc[mi][ni] = __builtin_amdgcn_mfma_f32_16x16x32_f16(af[mi], bfr[ni], acc[mi][ni], 0, 0, 0);
        __syncthreads();
    }

    // epilogue: C/D layout col=lane&15, row=quad*4+reg; write fp16 interleaved
    #pragma unroll
    for (int mi = 0; mi < 4; ++mi) {
        const int gmBase = o0 + wr + mi * 16 + quad * 4;   // 4 consecutive rows
        int ch0;
        unsigned short* base;
        if (isQ)              { ch0 = gmBase;       base = qi; }
        else if (gmBase < 256){ ch0 = gmBase;       base = ki; }
        else                  { ch0 = gmBase - 256; base = vi; }
        const int g   = ch0 >> 5;
        const int sub = (ch0 >> 3) & 3;
        const int l8  = ch0 & 7;                            // 0 or 4
        unsigned short* pbase = base + ((((size_t)b * 8 + g) * 4 + sub) * Pstr) * 8 + l8;
        #pragma unroll
        for (int ni = 0; ni < 4; ++ni) {
            const int gn = n0 + wc + ni * 16 + lrow;
            if (gn < Nreal) {
                ushort4 pk;
                pk.x = f2h(acc[mi][ni][0]);
                pk.y = f2h(acc[mi][ni][1]);
                pk.z = f2h(acc[mi][ni][2]);
                pk.w = f2h(acc[mi][ni][3]);
                *(ushort4*)(pbase + (size_t)gn * 8) = pk;
            }
        }
    }
}

// ---------------------------------------------------------------------------
// Grouped 7x7 attention, fp16 interleaved K/V, channel-split 4-barrier pipe.
// Block = 2 pixel rows x 56 cols for one (b,g): 128 threads, 112 active.
// LDS: f16x8 sbuf[2 halves][2 subs x 496 pos] = 31,744 B (~5 blocks/CU).
// Staging per half = contiguous copy of 2 subs x 496 x 16B (coalesced b128).
// QK via v_dot2_f32_f16 (fp32 acc); PV unpacked fp32 FMA.
// ---------------------------------------------------------------------------
#define NPOS 496   // 8 * 62
__global__ __launch_bounds__(128) void attn_kernel(const unsigned short* __restrict__ qi,
                                                   const unsigned short* __restrict__ ki,
                                                   const unsigned short* __restrict__ vi,
                                                   const float* __restrict__ rel_h,
                                                   const float* __restrict__ rel_w,
                                                   float* __restrict__ out) {
    __shared__ f16x8 sbuf[2 * 992];    // 31,744 B

    const int b  = blockIdx.z;
    const int g  = blockIdx.y;
    const int r0 = blockIdx.x * 2;
    const int oc0 = g * CG;
    const int tid = threadIdx.x;
    const bool active = tid < 112;
    const int rr = tid / 56;
    const int cx = tid - rr * 56;
    const int pix = (r0 + rr) * W + cx;

    const size_t bg4 = ((size_t)b * 8 + g) * 4;
    const size_t rowoff8 = ((size_t)r0 * WP) * 8;

    f16x8* bufA = sbuf;
    f16x8* bufB = sbuf + 992;

    // q: 4 subs x 8ch fp16 for this pixel (issued before staging barrier)
    f16x8 qh[4];
    if (active) {
        #pragma unroll
        for (int sub = 0; sub < 4; ++sub)
            qh[sub] = *(const f16x8*)(qi + ((bg4 + sub) * P1 + pix) * 8);
    }

    f16x8 st[8];
    // ---- stage K half A (subs 0,1) ----
    {
        const unsigned short* gb = ki + bg4 * P2 * 8 + rowoff8;
        #pragma unroll
        for (int it = 0; it < 8; ++it) {
            const int e = tid + it * 128;
            if (e < 992) {
                const int sl = (e >= 496);
                const int pos = e - (sl ? 496 : 0);
                st[it] = *(const f16x8*)(gb + ((size_t)sl * P2 + pos) * 8);
            }
        }
        #pragma unroll
        for (int it = 0; it < 8; ++it) {
            const int e = tid + it * 128;
            if (e < 992) bufA[e] = st[it];
        }
    }
    __syncthreads();   // B1: K-A ready

    // issue K half B loads (subs 2,3)
    {
        const unsigned short* gb = ki + (bg4 + 2) * P2 * 8 + rowoff8;
        #pragma unroll
        for (int it = 0; it < 8; ++it) {
            const int e = tid + it * 128;
            if (e < 992) {
                const int sl = (e >= 496);
                const int pos = e - (sl ? 496 : 0);
                st[it] = *(const f16x8*)(gb + ((size_t)sl * P2 + pos) * 8);
            }
        }
    }

    float logits[KS * KS];
    if (active) {
        // bias init: logits[t] = sum_c q[c] * rel[c][tap-row-or-col]
        const float* rel = (g < 4) ? (rel_h + oc0 * KS) : (rel_w + (oc0 - 128) * KS);
        float qf[32];
        #pragma unroll
        for (int sub = 0; sub < 4; ++sub)
            #pragma unroll
            for (int j = 0; j < 8; ++j)
                qf[sub * 8 + j] = (float)qh[sub][j];
        float biasdot[KS];
        #pragma unroll
        for (int t = 0; t < KS; ++t) {
            float s = 0.f;
            #pragma unroll
            for (int c = 0; c < 32; ++c) s += qf[c] * rel[c * KS + t];
            biasdot[t] = s;
        }
        #pragma unroll
        for (int i = 0; i < KS; ++i)
            #pragma unroll
            for (int j = 0; j < KS; ++j)
                logits[i * KS + j] = (g < 4) ? biasdot[i] : biasdot[j];

        // QK half A: subs 0,1
        #pragma unroll
        for (int sl = 0; sl < 2; ++sl) {
            const f16x8 qv = qh[sl];
            const h2 q0 = {qv[0], qv[1]}, q1 = {qv[2], qv[3]};
            const h2 q2 = {qv[4], qv[5]}, q3 = {qv[6], qv[7]};
            #pragma unroll
            for (int i = 0; i < KS; ++i) {
                const int eb = sl * NPOS + (rr + i) * WP + cx;
                #pragma unroll
                for (int j = 0; j < KS; ++j) {
                    const f16x8 kv = bufA[eb + j];
                    float s = logits[i * KS + j];
                    s = fdot2(q0, (h2){kv[0], kv[1]}, s);
                    s = fdot2(q1, (h2){kv[2], kv[3]}, s);
                    s = fdot2(q2, (h2){kv[4], kv[5]}, s);
                    s = fdot2(q3, (h2){kv[6], kv[7]}, s);
                    logits[i * KS + j] = s;
                }
            }
        }
    }
    // write K half B
    #pragma unroll
    for (int it = 0; it < 8; ++it) {
        const int e = tid + it * 128;
        if (e < 992) bufB[e] = st[it];
    }
    __syncthreads();   // B2: K-B ready

    // issue V half A loads (subs 0,1)
    {
        const unsigned short* gb = vi + bg4 * P2 * 8 + rowoff8;
        #pragma unroll
        for (int it = 0; it < 8; ++it) {
            const int e = tid + it * 128;
            if (e < 992) {
                const int sl = (e >= 496);
                const int pos = e - (sl ? 496 : 0);
                st[it] = *(const f16x8*)(gb + ((size_t)sl * P2 + pos) * 8);
            }
        }
    }

    if (active) {
        // QK half B: subs 2,3
        #pragma unroll
        for (int sl = 0; sl < 2; ++sl) {
            const f16x8 qv = qh[2 + sl];
            const h2 q0 = {qv[0], qv[1]}, q1 = {qv[2], qv[3]};
            const h2 q2 = {qv[4], qv[5]}, q3 = {qv[6], qv[7]};
            #pragma unroll
            for (int i = 0; i < KS; ++i) {
                const int eb = sl * NPOS + (rr + i) * WP + cx;
                #pragma unroll
                for (int j = 0; j < KS; ++j) {
                    const f16x8 kv = bufB[eb + j];
                    float s = logits[i * KS + j];
                    s = fdot2(q0, (h2){kv[0], kv[1]}, s);
                    s = fdot2(q1, (h2){kv[2], kv[3]}, s);
                    s = fdot2(q2, (h2){kv[4], kv[5]}, s);
                    s = fdot2(q3, (h2){kv[6], kv[7]}, s);
                    logits[i * KS + j] = s;
                }
            }
        }
        // softmax over 49 taps
        float m = logits[0];
        #pragma unroll
        for (int t = 1; t < KS * KS; ++t) m = fmaxf(m, logits[t]);
        float sum = 0.f;
        #pragma unroll
        for (int t = 0; t < KS * KS; ++t) {
            const float e = __expf(logits[t] - m);
            logits[t] = e;
            sum += e;
        }
        const float inv = 1.f / sum;
        #pragma unroll
        for (int t = 0; t < KS * KS; ++t) logits[t] *= inv;
    }
    // write V half A
    #pragma unroll
    for (int it = 0; it < 8; ++it) {
        const int e = tid + it * 128;
        if (e < 992) bufA[e] = st[it];
    }
    __syncthreads();   // B3: V-A ready

    // issue V half B loads (subs 2,3)
    {
        const unsigned short* gb = vi + (bg4 + 2) * P2 * 8 + rowoff8;
        #pragma unroll
        for (int it = 0; it < 8; ++it) {
            const int e = tid + it * 128;
            if (e < 992) {
                const int sl = (e >= 496);
                const int pos = e - (sl ? 496 : 0);
                st[it] = *(const f16x8*)(gb + ((size_t)sl * P2 + pos) * 8);
            }
        }
    }

    if (active) {
        // PV half A: subs 0,1 -> channels oc0+0..15
        #pragma unroll
        for (int sl = 0; sl < 2; ++sl) {
            float a[8] = {};
            #pragma unroll
            for (int i = 0; i < KS; ++i) {
                const int eb = sl * NPOS + (rr + i) * WP + cx;
                #pragma unroll
                for (int j = 0; j < KS; ++j) {
                    const f16x8 v = bufA[eb + j];
                    const float wt = logits[i * KS + j];
                    #pragma unroll
                    for (int c = 0; c < 8; ++c) a[c] += wt * (float)v[c];
                }
            }
            float* op = out + ((size_t)b * OUTC + oc0 + sl * 8) * P1 + pix;
            #pragma unroll
            for (int c = 0; c < 8; ++c) op[(size_t)c * P1] = a[c];
        }
    }
    // write V half B
    #pragma unroll
    for (int it = 0; it < 8; ++it) {
        const int e = tid + it * 128;
        if (e < 992) bufB[e] = st[it];
    }
    __syncthreads();   // B4: V-B ready

    if (active) {
        // PV half B: subs 2,3 -> channels oc0+16..31
        #pragma unroll
        for (int sl = 0; sl < 2; ++sl) {
            float a[8] = {};
            #pragma unroll
            for (int i = 0; i < KS; ++i) {
                const int eb = sl * NPOS + (rr + i) * WP + cx;
                #pragma unroll
                for (int j = 0; j < KS; ++j) {
                    const f16x8 v = bufB[eb + j];
                    const float wt = logits[i * KS + j];
                    #pragma unroll
                    for (int c = 0; c < 8; ++c) a[c] += wt * (float)v[c];
                }
            }
            float* op = out + ((size_t)b * OUTC + oc0 + 16 + sl * 8) * P1 + pix;
            #pragma unroll
            for (int c = 0; c < 8; ++c) op[(size_t)c * P1] = a[c];
        }
    }
}

extern "C" void kernel_launch(void* const* d_in, const int* in_sizes, int n_in,
                              void* d_out, int out_size, void* d_ws, size_t ws_size,
                              hipStream_t stream) {
    const float* fm = (const float*)d_in[0];
    const float* wq = (const float*)d_in[1];
    const float* wk = (const float*)d_in[2];
    const float* wv = (const float*)d_in[3];
    const float* rh = (const float*)d_in[4];
    const float* rw = (const float*)d_in[5];
    float* out = (float*)d_out;

    unsigned short* ws = (unsigned short*)d_ws;
    unsigned short* xt1  = ws;                               // 2*3200*256
    unsigned short* xt0  = xt1 + (size_t)B * N1PAD * CIN;    // 2*3968*256
    unsigned short* wqb  = xt0 + (size_t)B * N0PAD * CIN;    // 256*256
    unsigned short* wkvb = wqb + (size_t)OUTC * CIN;         // 512*256
    unsigned short* qi   = wkvb + (size_t)2 * OUTC * CIN;    // 2*8*4*3136*8
    unsigned short* ki   = qi + (size_t)B * OUTC * P1;       // 2*8*4*3844*8
    unsigned short* vi   = ki + (size_t)B * OUTC * P2;

    prep_kernel<<<1888, 256, 0, stream>>>(fm, wq, wk, wv, xt1, xt0, wqb, wkvb);
    gemm_kernel<<<dim3(31, 6, B), 256, 0, stream>>>(wqb, wkvb, xt1, xt0, qi, ki, vi);
    attn_kernel<<<dim3(H / 2, G, B), 128, 0, stream>>>(qi, ki, vi, rh, rw, out);
}

// Round 9
// 109.217 us; speedup vs baseline: 2.1310x; 1.0259x over previous
//
#include <hip/hip_runtime.h>
#include <hip/hip_bf16.h>

// Problem constants
#define B    2
#define CIN  256
#define H    56
#define W    56
#define OUTC 256
#define KS   7
#define PAD  3
#define G    8
#define CG   32
#define HP   62           // H + 2*PAD
#define WP   62
#define P1   (H * W)      // 3136
#define P2   (HP * WP)    // 3844

typedef __attribute__((ext_vector_type(2))) _Float16 h2;
typedef __attribute__((ext_vector_type(8))) _Float16 f16x8;
typedef __attribute__((ext_vector_type(8))) unsigned short ushort8;
typedef __attribute__((ext_vector_type(4))) float f32x4;

__device__ inline unsigned short f2h(float f) {    // RNE float->fp16 bits
    const _Float16 h = (_Float16)f;
    return *(const unsigned short*)&h;
}

__device__ inline float fdot2(h2 a, h2 b, float c) {
#if defined(__has_builtin)
#if __has_builtin(__builtin_amdgcn_fdot2)
    return __builtin_amdgcn_fdot2(a, b, c, false);
#else
    return c + (float)a[0] * (float)b[0] + (float)a[1] * (float)b[1];
#endif
#else
    return c + (float)a[0] * (float)b[0] + (float)a[1] * (float)b[1];
#endif
}

// ---------------------------------------------------------------------------
// Fused fp32->fp16 + MFMA GEMM (one launch): grid (31, 6, B).
//   y<2  : q GEMM  (w_q x fm_t1), x<25 only (N=P1)
//   y>=2 : kv GEMM (w_k rows 0..255, w_v rows 256..511 x padded fm_t0, N=P2)
// 128x128 tile, 4 waves, BK=32. Staging converts fp32 inputs inline:
//   A: weight rows are k-contiguous -> 4x float4 + cvt + 2x b128 LDS writes.
//   B: per-thread 16-channel gather from fm (SGPR channel bases, lane-
//      consecutive pixel offsets -> coalesced), zero for pad/oob pixels.
// Register prefetch of next K-step drains under MFMA.
// Epilogue writes fp16 INTERLEAVED planes: base[((b*8+g)*4+sub)*Pstr + n]*8+l8
// where ch = g*32 + sub*8 + l8. q rows -> qi ; kv rows <256 -> ki else vi.
// ---------------------------------------------------------------------------
#define ASTR 40
__global__ __launch_bounds__(256, 2) void gemm_kernel(const float* __restrict__ fm,
                                                      const float* __restrict__ wq,
                                                      const float* __restrict__ wk,
                                                      const float* __restrict__ wv,
                                                      unsigned short* __restrict__ qi,
                                                      unsigned short* __restrict__ ki,
                                                      unsigned short* __restrict__ vi) {
    const int b = blockIdx.z;
    const bool isQ = blockIdx.y < 2;
    if (isQ && blockIdx.x >= 25) return;
    const int o0 = (isQ ? blockIdx.y : (blockIdx.y - 2)) * 128;   // 0..383
    const int n0 = blockIdx.x * 128;
    const int Nreal = isQ ? P1 : P2;
    const int Pstr  = isQ ? P1 : P2;

    // weight source for this 128-row block
    const float* Wsrc;
    int orow0;
    if (isQ)            { Wsrc = wq; orow0 = o0; }
    else if (o0 < 256)  { Wsrc = wk; orow0 = o0; }
    else                { Wsrc = wv; orow0 = o0 - 256; }

    __shared__ unsigned short Alds[128 * ASTR];
    __shared__ unsigned short Blds[128 * ASTR];
    const int tid = threadIdx.x;
    const int lane = tid & 63;
    const int wave = tid >> 6;
    const int wr = (wave >> 1) * 64;
    const int wc = (wave & 1) * 64;
    const int lrow = lane & 15;
    const int quad = lane >> 4;

    // staging map: row = tid&127 (lane-consecutive), 16-ch half = tid>>7
    const int arow = tid & 127;
    const int akc  = (tid >> 7) * 16;

    // B-side pixel -> fm offset (constant over K)
    const int n = n0 + arow;
    int srcoff = -1;
    if (isQ) {
        if (n < P1) srcoff = n;
    } else {
        if (n < P2) {
            const int y = n / WP, x = n - y * WP;
            const int iy = y - PAD, ix = x - PAD;
            if (iy >= 0 && iy < H && ix >= 0 && ix < W) srcoff = iy * W + ix;
        }
    }
    const float* fmB = fm + ((size_t)b * (2 * CIN) + (isQ ? CIN : 0)) * P1;  // channel base
    const float* wrow = Wsrc + (size_t)orow0 * CIN + (size_t)arow * CIN + akc;

    unsigned short* alp = Alds + arow * ASTR + akc;
    unsigned short* blp = Blds + arow * ASTR + akc;

    f32x4 acc[4][4] = {};

    float av[16], bv[16];
    {   // K-step 0 loads
        const float4 a0 = ((const float4*)wrow)[0];
        const float4 a1 = ((const float4*)wrow)[1];
        const float4 a2 = ((const float4*)wrow)[2];
        const float4 a3 = ((const float4*)wrow)[3];
        av[0]=a0.x; av[1]=a0.y; av[2]=a0.z; av[3]=a0.w;
        av[4]=a1.x; av[5]=a1.y; av[6]=a1.z; av[7]=a1.w;
        av[8]=a2.x; av[9]=a2.y; av[10]=a2.z; av[11]=a2.w;
        av[12]=a3.x; av[13]=a3.y; av[14]=a3.z; av[15]=a3.w;
        #pragma unroll
        for (int j = 0; j < 16; ++j)
            bv[j] = (srcoff >= 0) ? fmB[(size_t)(akc + j) * P1 + srcoff] : 0.f;
    }

    for (int kb = 0; kb < CIN / 32; ++kb) {
        {   // convert + LDS write
            f16x8 p0, p1, p2, p3;
            #pragma unroll
            for (int j = 0; j < 8; ++j) {
                p0[j] = (_Float16)av[j];
                p1[j] = (_Float16)av[8 + j];
                p2[j] = (_Float16)bv[j];
                p3[j] = (_Float16)bv[8 + j];
            }
            *(f16x8*)(alp)     = p0;
            *(f16x8*)(alp + 8) = p1;
            *(f16x8*)(blp)     = p2;
            *(f16x8*)(blp + 8) = p3;
        }
        __syncthreads();
        if (kb < CIN / 32 - 1) {   // prefetch next K-step (drains under MFMA)
            const int c0 = (kb + 1) * 32 + akc;
            const float* wnext = wrow + (kb + 1) * 32;
            const float4 a0 = ((const float4*)wnext)[0];
            const float4 a1 = ((const float4*)wnext)[1];
            const float4 a2 = ((const float4*)wnext)[2];
            const float4 a3 = ((const float4*)wnext)[3];
            av[0]=a0.x; av[1]=a0.y; av[2]=a0.z; av[3]=a0.w;
            av[4]=a1.x; av[5]=a1.y; av[6]=a1.z; av[7]=a1.w;
            av[8]=a2.x; av[9]=a2.y; av[10]=a2.z; av[11]=a2.w;
            av[12]=a3.x; av[13]=a3.y; av[14]=a3.z; av[15]=a3.w;
            #pragma unroll
            for (int j = 0; j < 16; ++j)
                bv[j] = (srcoff >= 0) ? fmB[(size_t)(c0 + j) * P1 + srcoff] : 0.f;
        }
        f16x8 af[4], bfr[4];
        #pragma unroll
        for (int mi = 0; mi < 4; ++mi)
            af[mi] = *(const f16x8*)&Alds[(wr + mi * 16 + lrow) * ASTR + quad * 8];
        #pragma unroll
        for (int ni = 0; ni < 4; ++ni)
            bfr[ni] = *(const f16x8*)&Blds[(wc + ni * 16 + lrow) * ASTR + quad * 8];
        #pragma unroll
        for (int mi = 0; mi < 4; ++mi)
            #pragma unroll
            for (int ni = 0; ni < 4; ++ni)
                acc[mi][ni] = __builtin_amdgcn_mfma_f32_16x16x32_f16(af[mi], bfr[ni], acc[mi][ni], 0, 0, 0);
        __syncthreads();
    }

    // epilogue: C/D layout col=lane&15, row=quad*4+reg; write fp16 interleaved
    #pragma unroll
    for (int mi = 0; mi < 4; ++mi) {
        const int gmBase = o0 + wr + mi * 16 + quad * 4;   // 4 consecutive rows
        int ch0;
        unsigned short* base;
        if (isQ)               { ch0 = gmBase;       base = qi; }
        else if (gmBase < 256) { ch0 = gmBase;       base = ki; }
        else                   { ch0 = gmBase - 256; base = vi; }
        const int g   = ch0 >> 5;
        const int sub = (ch0 >> 3) & 3;
        const int l8  = ch0 & 7;                            // 0 or 4
        unsigned short* pbase = base + ((((size_t)b * 8 + g) * 4 + sub) * Pstr) * 8 + l8;
        #pragma unroll
        for (int ni = 0; ni < 4; ++ni) {
            const int gn = n0 + wc + ni * 16 + lrow;
            if (gn < Nreal) {
                ushort4 pk;
                pk.x = f2h(acc[mi][ni][0]);
                pk.y = f2h(acc[mi][ni][1]);
                pk.z = f2h(acc[mi][ni][2]);
                pk.w = f2h(acc[mi][ni][3]);
                *(ushort4*)(pbase + (size_t)gn * 8) = pk;
            }
        }
    }
}

// ---------------------------------------------------------------------------
// Grouped 7x7 attention, fp16 interleaved K/V, channel-split 4-barrier pipe.
// Block = 2 pixel rows x 56 cols for one (b,g): 128 threads, 112 active.
// LDS: f16x8 sbuf[2 halves][2 subs x 496 pos] = 31,744 B (~5 blocks/CU).
// Staging per half = contiguous copy of 2 subs x 496 x 16B (coalesced b128).
// QK via v_dot2_f32_f16 (fp32 acc); PV unpacked fp32 FMA.
// ---------------------------------------------------------------------------
#define NPOS 496   // 8 * 62
__global__ __launch_bounds__(128) void attn_kernel(const unsigned short* __restrict__ qi,
                                                   const unsigned short* __restrict__ ki,
                                                   const unsigned short* __restrict__ vi,
                                                   const float* __restrict__ rel_h,
                                                   const float* __restrict__ rel_w,
                                                   float* __restrict__ out) {
    __shared__ f16x8 sbuf[2 * 992];    // 31,744 B

    const int b  = blockIdx.z;
    const int g  = blockIdx.y;
    const int r0 = blockIdx.x * 2;
    const int oc0 = g * CG;
    const int tid = threadIdx.x;
    const bool active = tid < 112;
    const int rr = tid / 56;
    const int cx = tid - rr * 56;
    const int pix = (r0 + rr) * W + cx;

    const size_t bg4 = ((size_t)b * 8 + g) * 4;
    const size_t rowoff8 = ((size_t)r0 * WP) * 8;

    f16x8* bufA = sbuf;
    f16x8* bufB = sbuf + 992;

    // q: 4 subs x 8ch fp16 for this pixel (issued before staging barrier)
    f16x8 qh[4];
    if (active) {
        #pragma unroll
        for (int sub = 0; sub < 4; ++sub)
            qh[sub] = *(const f16x8*)(qi + ((bg4 + sub) * P1 + pix) * 8);
    }

    f16x8 st[8];
    // ---- stage K half A (subs 0,1) ----
    {
        const unsigned short* gb = ki + bg4 * P2 * 8 + rowoff8;
        #pragma unroll
        for (int it = 0; it < 8; ++it) {
            const int e = tid + it * 128;
            if (e < 992) {
                const int sl = (e >= 496);
                const int pos = e - (sl ? 496 : 0);
                st[it] = *(const f16x8*)(gb + ((size_t)sl * P2 + pos) * 8);
            }
        }
        #pragma unroll
        for (int it = 0; it < 8; ++it) {
            const int e = tid + it * 128;
            if (e < 992) bufA[e] = st[it];
        }
    }
    __syncthreads();   // B1: K-A ready

    // issue K half B loads (subs 2,3)
    {
        const unsigned short* gb = ki + (bg4 + 2) * P2 * 8 + rowoff8;
        #pragma unroll
        for (int it = 0; it < 8; ++it) {
            const int e = tid + it * 128;
            if (e < 992) {
                const int sl = (e >= 496);
                const int pos = e - (sl ? 496 : 0);
                st[it] = *(const f16x8*)(gb + ((size_t)sl * P2 + pos) * 8);
            }
        }
    }

    float logits[KS * KS];
    if (active) {
        // bias init: logits[t] = sum_c q[c] * rel[c][tap-row-or-col]
        const float* rel = (g < 4) ? (rel_h + oc0 * KS) : (rel_w + (oc0 - 128) * KS);
        float qf[32];
        #pragma unroll
        for (int sub = 0; sub < 4; ++sub)
            #pragma unroll
            for (int j = 0; j < 8; ++j)
                qf[sub * 8 + j] = (float)qh[sub][j];
        float biasdot[KS];
        #pragma unroll
        for (int t = 0; t < KS; ++t) {
            float s = 0.f;
            #pragma unroll
            for (int c = 0; c < 32; ++c) s += qf[c] * rel[c * KS + t];
            biasdot[t] = s;
        }
        #pragma unroll
        for (int i = 0; i < KS; ++i)
            #pragma unroll
            for (int j = 0; j < KS; ++j)
                logits[i * KS + j] = (g < 4) ? biasdot[i] : biasdot[j];

        // QK half A: subs 0,1
        #pragma unroll
        for (int sl = 0; sl < 2; ++sl) {
            const f16x8 qv = qh[sl];
            const h2 q0 = {qv[0], qv[1]}, q1 = {qv[2], qv[3]};
            const h2 q2 = {qv[4], qv[5]}, q3 = {qv[6], qv[7]};
            #pragma unroll
            for (int i = 0; i < KS; ++i) {
                const int eb = sl * NPOS + (rr + i) * WP + cx;
                #pragma unroll
                for (int j = 0; j < KS; ++j) {
                    const f16x8 kv = bufA[eb + j];
                    float s = logits[i * KS + j];
                    s = fdot2(q0, (h2){kv[0], kv[1]}, s);
                    s = fdot2(q1, (h2){kv[2], kv[3]}, s);
                    s = fdot2(q2, (h2){kv[4], kv[5]}, s);
                    s = fdot2(q3, (h2){kv[6], kv[7]}, s);
                    logits[i * KS + j] = s;
                }
            }
        }
    }
    // write K half B
    #pragma unroll
    for (int it = 0; it < 8; ++it) {
        const int e = tid + it * 128;
        if (e < 992) bufB[e] = st[it];
    }
    __syncthreads();   // B2: K-B ready

    // issue V half A loads (subs 0,1)
    {
        const unsigned short* gb = vi + bg4 * P2 * 8 + rowoff8;
        #pragma unroll
        for (int it = 0; it < 8; ++it) {
            const int e = tid + it * 128;
            if (e < 992) {
                const int sl = (e >= 496);
                const int pos = e - (sl ? 496 : 0);
                st[it] = *(const f16x8*)(gb + ((size_t)sl * P2 + pos) * 8);
            }
        }
    }

    if (active) {
        // QK half B: subs 2,3
        #pragma unroll
        for (int sl = 0; sl < 2; ++sl) {
            const f16x8 qv = qh[2 + sl];
            const h2 q0 = {qv[0], qv[1]}, q1 = {qv[2], qv[3]};
            const h2 q2 = {qv[4], qv[5]}, q3 = {qv[6], qv[7]};
            #pragma unroll
            for (int i = 0; i < KS; ++i) {
                const int eb = sl * NPOS + (rr + i) * WP + cx;
                #pragma unroll
                for (int j = 0; j < KS; ++j) {
                    const f16x8 kv = bufB[eb + j];
                    float s = logits[i * KS + j];
                    s = fdot2(q0, (h2){kv[0], kv[1]}, s);
                    s = fdot2(q1, (h2){kv[2], kv[3]}, s);
                    s = fdot2(q2, (h2){kv[4], kv[5]}, s);
                    s = fdot2(q3, (h2){kv[6], kv[7]}, s);
                    logits[i * KS + j] = s;
                }
            }
        }
        // softmax over 49 taps
        float m = logits[0];
        #pragma unroll
        for (int t = 1; t < KS * KS; ++t) m = fmaxf(m, logits[t]);
        float sum = 0.f;
        #pragma unroll
        for (int t = 0; t < KS * KS; ++t) {
            const float e = __expf(logits[t] - m);
            logits[t] = e;
            sum += e;
        }
        const float inv = 1.f / sum;
        #pragma unroll
        for (int t = 0; t < KS * KS; ++t) logits[t] *= inv;
    }
    // write V half A
    #pragma unroll
    for (int it = 0; it < 8; ++it) {
        const int e = tid + it * 128;
        if (e < 992) bufA[e] = st[it];
    }
    __syncthreads();   // B3: V-A ready

    // issue V half B loads (subs 2,3)
    {
        const unsigned short* gb = vi + (bg4 + 2) * P2 * 8 + rowoff8;
        #pragma unroll
        for (int it = 0; it < 8; ++it) {
            const int e = tid + it * 128;
            if (e < 992) {
                const int sl = (e >= 496);
                const int pos = e - (sl ? 496 : 0);
                st[it] = *(const f16x8*)(gb + ((size_t)sl * P2 + pos) * 8);
            }
        }
    }

    if (active) {
        // PV half A: subs 0,1 -> channels oc0+0..15
        #pragma unroll
        for (int sl = 0; sl < 2; ++sl) {
            float a[8] = {};
            #pragma unroll
            for (int i = 0; i < KS; ++i) {
                const int eb = sl * NPOS + (rr + i) * WP + cx;
                #pragma unroll
                for (int j = 0; j < KS; ++j) {
                    const f16x8 v = bufA[eb + j];
                    const float wt = logits[i * KS + j];
                    #pragma unroll
                    for (int c = 0; c < 8; ++c) a[c] += wt * (float)v[c];
                }
            }
            float* op = out + ((size_t)b * OUTC + oc0 + sl * 8) * P1 + pix;
            #pragma unroll
            for (int c = 0; c < 8; ++c) op[(size_t)c * P1] = a[c];
        }
    }
    // write V half B
    #pragma unroll
    for (int it = 0; it < 8; ++it) {
        const int e = tid + it * 128;
        if (e < 992) bufB[e] = st[it];
    }
    __syncthreads();   // B4: V-B ready

    if (active) {
        // PV half B: subs 2,3 -> channels oc0+16..31
        #pragma unroll
        for (int sl = 0; sl < 2; ++sl) {
            float a[8] = {};
            #pragma unroll
            for (int i = 0; i < KS; ++i) {
                const int eb = sl * NPOS + (rr + i) * WP + cx;
                #pragma unroll
                for (int j = 0; j < KS; ++j) {
                    const f16x8 v = bufB[eb + j];
                    const float wt = logits[i * KS + j];
                    #pragma unroll
                    for (int c = 0; c < 8; ++c) a[c] += wt * (float)v[c];
                }
            }
            float* op = out + ((size_t)b * OUTC + oc0 + 16 + sl * 8) * P1 + pix;
            #pragma unroll
            for (int c = 0; c < 8; ++c) op[(size_t)c * P1] = a[c];
        }
    }
}

extern "C" void kernel_launch(void* const* d_in, const int* in_sizes, int n_in,
                              void* d_out, int out_size, void* d_ws, size_t ws_size,
                              hipStream_t stream) {
    const float* fm = (const float*)d_in[0];
    const float* wq = (const float*)d_in[1];
    const float* wk = (const float*)d_in[2];
    const float* wv = (const float*)d_in[3];
    const float* rh = (const float*)d_in[4];
    const float* rw = (const float*)d_in[5];
    float* out = (float*)d_out;

    unsigned short* ws = (unsigned short*)d_ws;
    unsigned short* qi = ws;                             // 2*8*4*3136*8 fp16
    unsigned short* ki = qi + (size_t)B * OUTC * P1;     // 2*8*4*3844*8 fp16
    unsigned short* vi = ki + (size_t)B * OUTC * P2;

    gemm_kernel<<<dim3(31, 6, B), 256, 0, stream>>>(fm, wq, wk, wv, qi, ki, vi);
    attn_kernel<<<dim3(H / 2, G, B), 128, 0, stream>>>(qi, ki, vi, rh, rw, out);
}

// Round 10
// 104.945 us; speedup vs baseline: 2.2177x; 1.0407x over previous
//
#include <hip/hip_runtime.h>
#include <hip/hip_bf16.h>

// Problem constants
#define B    2
#define CIN  256
#define H    56
#define W    56
#define OUTC 256
#define KS   7
#define PAD  3
#define G    8
#define CG   32
#define HP   62           // H + 2*PAD
#define WP   62
#define P1   (H * W)      // 3136
#define P2   (HP * WP)    // 3844

typedef __attribute__((ext_vector_type(2))) _Float16 h2;
typedef __attribute__((ext_vector_type(8))) _Float16 f16x8;
typedef __attribute__((ext_vector_type(8))) unsigned short ushort8;
typedef __attribute__((ext_vector_type(4))) float f32x4;

__device__ inline unsigned short f2h(float f) {    // RNE float->fp16 bits
    const _Float16 h = (_Float16)f;
    return *(const unsigned short*)&h;
}

__device__ inline float fdot2(h2 a, h2 b, float c) {
#if defined(__has_builtin)
#if __has_builtin(__builtin_amdgcn_fdot2)
    return __builtin_amdgcn_fdot2(a, b, c, false);
#else
    return c + (float)a[0] * (float)b[0] + (float)a[1] * (float)b[1];
#endif
#else
    return c + (float)a[0] * (float)b[0] + (float)a[1] * (float)b[1];
#endif
}

__device__ inline float dot8(const f16x8 q, const f16x8 k, float s) {
    s = fdot2((h2){q[0], q[1]}, (h2){k[0], k[1]}, s);
    s = fdot2((h2){q[2], q[3]}, (h2){k[2], k[3]}, s);
    s = fdot2((h2){q[4], q[5]}, (h2){k[4], k[5]}, s);
    s = fdot2((h2){q[6], q[7]}, (h2){k[6], k[7]}, s);
    return s;
}

// ---------------------------------------------------------------------------
// Fused fp32->fp16 + MFMA GEMM (one launch): grid (31, 6, B).  (unchanged R9)
//   y<2  : q GEMM  (w_q x fm_t1), x<25 only (N=P1)
//   y>=2 : kv GEMM (w_k rows 0..255, w_v rows 256..511 x padded fm_t0, N=P2)
// 128x128 tile, 4 waves, BK=32; staging converts fp32 inputs inline.
// Epilogue writes fp16 INTERLEAVED planes: base[((b*8+g)*4+sub)*Pstr + n]*8+l8.
// ---------------------------------------------------------------------------
#define ASTR 40
__global__ __launch_bounds__(256, 2) void gemm_kernel(const float* __restrict__ fm,
                                                      const float* __restrict__ wq,
                                                      const float* __restrict__ wk,
                                                      const float* __restrict__ wv,
                                                      unsigned short* __restrict__ qi,
                                                      unsigned short* __restrict__ ki,
                                                      unsigned short* __restrict__ vi) {
    const int b = blockIdx.z;
    const bool isQ = blockIdx.y < 2;
    if (isQ && blockIdx.x >= 25) return;
    const int o0 = (isQ ? blockIdx.y : (blockIdx.y - 2)) * 128;   // 0..383
    const int n0 = blockIdx.x * 128;
    const int Nreal = isQ ? P1 : P2;
    const int Pstr  = isQ ? P1 : P2;

    const float* Wsrc;
    int orow0;
    if (isQ)            { Wsrc = wq; orow0 = o0; }
    else if (o0 < 256)  { Wsrc = wk; orow0 = o0; }
    else                { Wsrc = wv; orow0 = o0 - 256; }

    __shared__ unsigned short Alds[128 * ASTR];
    __shared__ unsigned short Blds[128 * ASTR];
    const int tid = threadIdx.x;
    const int lane = tid & 63;
    const int wave = tid >> 6;
    const int wr = (wave >> 1) * 64;
    const int wc = (wave & 1) * 64;
    const int lrow = lane & 15;
    const int quad = lane >> 4;

    const int arow = tid & 127;
    const int akc  = (tid >> 7) * 16;

    const int n = n0 + arow;
    int srcoff = -1;
    if (isQ) {
        if (n < P1) srcoff = n;
    } else {
        if (n < P2) {
            const int y = n / WP, x = n - y * WP;
            const int iy = y - PAD, ix = x - PAD;
            if (iy >= 0 && iy < H && ix >= 0 && ix < W) srcoff = iy * W + ix;
        }
    }
    const float* fmB = fm + ((size_t)b * (2 * CIN) + (isQ ? CIN : 0)) * P1;
    const float* wrow = Wsrc + (size_t)orow0 * CIN + (size_t)arow * CIN + akc;

    unsigned short* alp = Alds + arow * ASTR + akc;
    unsigned short* blp = Blds + arow * ASTR + akc;

    f32x4 acc[4][4] = {};

    float av[16], bv[16];
    {
        const float4 a0 = ((const float4*)wrow)[0];
        const float4 a1 = ((const float4*)wrow)[1];
        const float4 a2 = ((const float4*)wrow)[2];
        const float4 a3 = ((const float4*)wrow)[3];
        av[0]=a0.x; av[1]=a0.y; av[2]=a0.z; av[3]=a0.w;
        av[4]=a1.x; av[5]=a1.y; av[6]=a1.z; av[7]=a1.w;
        av[8]=a2.x; av[9]=a2.y; av[10]=a2.z; av[11]=a2.w;
        av[12]=a3.x; av[13]=a3.y; av[14]=a3.z; av[15]=a3.w;
        #pragma unroll
        for (int j = 0; j < 16; ++j)
            bv[j] = (srcoff >= 0) ? fmB[(size_t)(akc + j) * P1 + srcoff] : 0.f;
    }

    for (int kb = 0; kb < CIN / 32; ++kb) {
        {
            f16x8 p0, p1, p2, p3;
            #pragma unroll
            for (int j = 0; j < 8; ++j) {
                p0[j] = (_Float16)av[j];
                p1[j] = (_Float16)av[8 + j];
                p2[j] = (_Float16)bv[j];
                p3[j] = (_Float16)bv[8 + j];
            }
            *(f16x8*)(alp)     = p0;
            *(f16x8*)(alp + 8) = p1;
            *(f16x8*)(blp)     = p2;
            *(f16x8*)(blp + 8) = p3;
        }
        __syncthreads();
        if (kb < CIN / 32 - 1) {
            const int c0 = (kb + 1) * 32 + akc;
            const float* wnext = wrow + (kb + 1) * 32;
            const float4 a0 = ((const float4*)wnext)[0];
            const float4 a1 = ((const float4*)wnext)[1];
            const float4 a2 = ((const float4*)wnext)[2];
            const float4 a3 = ((const float4*)wnext)[3];
            av[0]=a0.x; av[1]=a0.y; av[2]=a0.z; av[3]=a0.w;
            av[4]=a1.x; av[5]=a1.y; av[6]=a1.z; av[7]=a1.w;
            av[8]=a2.x; av[9]=a2.y; av[10]=a2.z; av[11]=a2.w;
            av[12]=a3.x; av[13]=a3.y; av[14]=a3.z; av[15]=a3.w;
            #pragma unroll
            for (int j = 0; j < 16; ++j)
                bv[j] = (srcoff >= 0) ? fmB[(size_t)(c0 + j) * P1 + srcoff] : 0.f;
        }
        f16x8 af[4], bfr[4];
        #pragma unroll
        for (int mi = 0; mi < 4; ++mi)
            af[mi] = *(const f16x8*)&Alds[(wr + mi * 16 + lrow) * ASTR + quad * 8];
        #pragma unroll
        for (int ni = 0; ni < 4; ++ni)
            bfr[ni] = *(const f16x8*)&Blds[(wc + ni * 16 + lrow) * ASTR + quad * 8];
        #pragma unroll
        for (int mi = 0; mi < 4; ++mi)
            #pragma unroll
            for (int ni = 0; ni < 4; ++ni)
                acc[mi][ni] = __builtin_amdgcn_mfma_f32_16x16x32_f16(af[mi], bfr[ni], acc[mi][ni], 0, 0, 0);
        __syncthreads();
    }

    #pragma unroll
    for (int mi = 0; mi < 4; ++mi) {
        const int gmBase = o0 + wr + mi * 16 + quad * 4;
        int ch0;
        unsigned short* base;
        if (isQ)               { ch0 = gmBase;       base = qi; }
        else if (gmBase < 256) { ch0 = gmBase;       base = ki; }
        else                   { ch0 = gmBase - 256; base = vi; }
        const int g   = ch0 >> 5;
        const int sub = (ch0 >> 3) & 3;
        const int l8  = ch0 & 7;
        unsigned short* pbase = base + ((((size_t)b * 8 + g) * 4 + sub) * Pstr) * 8 + l8;
        #pragma unroll
        for (int ni = 0; ni < 4; ++ni) {
            const int gn = n0 + wc + ni * 16 + lrow;
            if (gn < Nreal) {
                ushort4 pk;
                pk.x = f2h(acc[mi][ni][0]);
                pk.y = f2h(acc[mi][ni][1]);
                pk.z = f2h(acc[mi][ni][2]);
                pk.w = f2h(acc[mi][ni][3]);
                *(ushort4*)(pbase + (size_t)gn * 8) = pk;
            }
        }
    }
}

// ---------------------------------------------------------------------------
// Grouped 7x7 attention v2: 2 vertically-adjacent pixels per thread.
// Block = 4 pixel rows x 56 cols for one (b,g): 128 threads, 112 active
// (rp = tid/56 selects row pair r0+2rp, r0+2rp+1; cx = tid%56).
// Window = 10 padded rows x 62 = 620 pos; halves of 16 ch (2 f16x8 subs).
// LDS: f16x8 sbuf[2 halves][2 subs x 620] = 39,680 B.
// Read sharing: per tap-col j, 8 row-reads (ii=0..7) serve pixel0 taps ii<7
// and pixel1 taps ii>=1 -> 1.75x fewer ds_read_b128 per output; lane stride
// stays 16 B (conflict-free). 4-barrier K/V channel-split pipeline as before.
// ---------------------------------------------------------------------------
#define NPOS4 620    // 10 * 62
#define HALFE 1240   // 2 subs * 620
__global__ __launch_bounds__(128) void attn_kernel(const unsigned short* __restrict__ qi,
                                                   const unsigned short* __restrict__ ki,
                                                   const unsigned short* __restrict__ vi,
                                                   const float* __restrict__ rel_h,
                                                   const float* __restrict__ rel_w,
                                                   float* __restrict__ out) {
    __shared__ f16x8 sbuf[2 * HALFE];   // 39,680 B

    const int b  = blockIdx.z;
    const int g  = blockIdx.y;
    const int r0 = blockIdx.x * 4;      // first pixel row of 4-row strip
    const int oc0 = g * CG;
    const int tid = threadIdx.x;
    const bool active = tid < 112;
    const int rp = tid / 56;            // 0..1 row-pair in strip
    const int cx = tid - rp * 56;       // 0..55
    const int pr0 = r0 + 2 * rp;        // pixel rows pr0, pr0+1
    const int pix0 = pr0 * W + cx;
    const int pix1 = pix0 + W;

    const size_t bg4 = ((size_t)b * 8 + g) * 4;
    const size_t rowoff8 = ((size_t)r0 * WP) * 8;

    f16x8* bufA = sbuf;
    f16x8* bufB = sbuf + HALFE;

    // q for both pixels (issued before staging barrier)
    f16x8 qh0[4], qh1[4];
    if (active) {
        #pragma unroll
        for (int sub = 0; sub < 4; ++sub) {
            qh0[sub] = *(const f16x8*)(qi + ((bg4 + sub) * P1 + pix0) * 8);
            qh1[sub] = *(const f16x8*)(qi + ((bg4 + sub) * P1 + pix1) * 8);
        }
    }

    f16x8 st[10];
    // ---- stage K half A (subs 0,1) ----
    {
        const unsigned short* gb = ki + bg4 * P2 * 8 + rowoff8;
        #pragma unroll
        for (int it = 0; it < 10; ++it) {
            const int e = tid + it * 128;
            if (e < HALFE) {
                const int sl = (e >= NPOS4);
                const int pos = e - (sl ? NPOS4 : 0);
                st[it] = *(const f16x8*)(gb + ((size_t)sl * P2 + pos) * 8);
            }
        }
        #pragma unroll
        for (int it = 0; it < 10; ++it) {
            const int e = tid + it * 128;
            if (e < HALFE) bufA[e] = st[it];
        }
    }
    __syncthreads();   // B1: K-A ready

    // issue K half B loads (subs 2,3)
    {
        const unsigned short* gb = ki + (bg4 + 2) * P2 * 8 + rowoff8;
        #pragma unroll
        for (int it = 0; it < 10; ++it) {
            const int e = tid + it * 128;
            if (e < HALFE) {
                const int sl = (e >= NPOS4);
                const int pos = e - (sl ? NPOS4 : 0);
                st[it] = *(const f16x8*)(gb + ((size_t)sl * P2 + pos) * 8);
            }
        }
    }

    float logits0[KS * KS], logits1[KS * KS];
    if (active) {
        // bias init per pixel (shared rel loads)
        const float* rel = (g < 4) ? (rel_h + oc0 * KS) : (rel_w + (oc0 - 128) * KS);
        float qf0[32], qf1[32];
        #pragma unroll
        for (int sub = 0; sub < 4; ++sub)
            #pragma unroll
            for (int j = 0; j < 8; ++j) {
                qf0[sub * 8 + j] = (float)qh0[sub][j];
                qf1[sub * 8 + j] = (float)qh1[sub][j];
            }
        float bd0[KS], bd1[KS];
        #pragma unroll
        for (int t = 0; t < KS; ++t) {
            float s0 = 0.f, s1 = 0.f;
            #pragma unroll
            for (int c = 0; c < 32; ++c) {
                const float r = rel[c * KS + t];
                s0 += qf0[c] * r;
                s1 += qf1[c] * r;
            }
            bd0[t] = s0; bd1[t] = s1;
        }
        #pragma unroll
        for (int i = 0; i < KS; ++i)
            #pragma unroll
            for (int j = 0; j < KS; ++j) {
                logits0[i * KS + j] = (g < 4) ? bd0[i] : bd0[j];
                logits1[i * KS + j] = (g < 4) ? bd1[i] : bd1[j];
            }

        // QK half A: subs 0,1 — row-shared reads
        #pragma unroll
        for (int s = 0; s < 2; ++s) {
            const f16x8 q0 = qh0[s];
            const f16x8 q1 = qh1[s];
            #pragma unroll
            for (int j = 0; j < KS; ++j) {
                #pragma unroll
                for (int ii = 0; ii < 8; ++ii) {
                    const f16x8 kv = bufA[s * NPOS4 + (2 * rp + ii) * WP + cx + j];
                    if (ii < 7)  logits0[ii * KS + j]       = dot8(q0, kv, logits0[ii * KS + j]);
                    if (ii >= 1) logits1[(ii - 1) * KS + j] = dot8(q1, kv, logits1[(ii - 1) * KS + j]);
                }
            }
        }
    }
    // write K half B
    #pragma unroll
    for (int it = 0; it < 10; ++it) {
        const int e = tid + it * 128;
        if (e < HALFE) bufB[e] = st[it];
    }
    __syncthreads();   // B2: K-B ready

    // issue V half A loads (subs 0,1)
    {
        const unsigned short* gb = vi + bg4 * P2 * 8 + rowoff8;
        #pragma unroll
        for (int it = 0; it < 10; ++it) {
            const int e = tid + it * 128;
            if (e < HALFE) {
                const int sl = (e >= NPOS4);
                const int pos = e - (sl ? NPOS4 : 0);
                st[it] = *(const f16x8*)(gb + ((size_t)sl * P2 + pos) * 8);
            }
        }
    }

    if (active) {
        // QK half B: subs 2,3
        #pragma unroll
        for (int s = 0; s < 2; ++s) {
            const f16x8 q0 = qh0[2 + s];
            const f16x8 q1 = qh1[2 + s];
            #pragma unroll
            for (int j = 0; j < KS; ++j) {
                #pragma unroll
                for (int ii = 0; ii < 8; ++ii) {
                    const f16x8 kv = bufB[s * NPOS4 + (2 * rp + ii) * WP + cx + j];
                    if (ii < 7)  logits0[ii * KS + j]       = dot8(q0, kv, logits0[ii * KS + j]);
                    if (ii >= 1) logits1[(ii - 1) * KS + j] = dot8(q1, kv, logits1[(ii - 1) * KS + j]);
                }
            }
        }
        // softmax per pixel
        {
            float m = logits0[0];
            #pragma unroll
            for (int t = 1; t < KS * KS; ++t) m = fmaxf(m, logits0[t]);
            float sum = 0.f;
            #pragma unroll
            for (int t = 0; t < KS * KS; ++t) {
                const float e = __expf(logits0[t] - m);
                logits0[t] = e;
                sum += e;
            }
            const float inv = 1.f / sum;
            #pragma unroll
            for (int t = 0; t < KS * KS; ++t) logits0[t] *= inv;
        }
        {
            float m = logits1[0];
            #pragma unroll
            for (int t = 1; t < KS * KS; ++t) m = fmaxf(m, logits1[t]);
            float sum = 0.f;
            #pragma unroll
            for (int t = 0; t < KS * KS; ++t) {
                const float e = __expf(logits1[t] - m);
                logits1[t] = e;
                sum += e;
            }
            const float inv = 1.f / sum;
            #pragma unroll
            for (int t = 0; t < KS * KS; ++t) logits1[t] *= inv;
        }
    }
    // write V half A
    #pragma unroll
    for (int it = 0; it < 10; ++it) {
        const int e = tid + it * 128;
        if (e < HALFE) bufA[e] = st[it];
    }
    __syncthreads();   // B3: V-A ready

    // issue V half B loads (subs 2,3)
    {
        const unsigned short* gb = vi + (bg4 + 2) * P2 * 8 + rowoff8;
        #pragma unroll
        for (int it = 0; it < 10; ++it) {
            const int e = tid + it * 128;
            if (e < HALFE) {
                const int sl = (e >= NPOS4);
                const int pos = e - (sl ? NPOS4 : 0);
                st[it] = *(const f16x8*)(gb + ((size_t)sl * P2 + pos) * 8);
            }
        }
    }

    if (active) {
        // PV half A: subs 0,1 -> channels oc0 + s*8
        #pragma unroll
        for (int s = 0; s < 2; ++s) {
            float a0[8] = {}, a1[8] = {};
            #pragma unroll
            for (int j = 0; j < KS; ++j) {
                #pragma unroll
                for (int ii = 0; ii < 8; ++ii) {
                    const f16x8 v = bufA[s * NPOS4 + (2 * rp + ii) * WP + cx + j];
                    if (ii < 7) {
                        const float wt = logits0[ii * KS + j];
                        #pragma unroll
                        for (int c = 0; c < 8; ++c) a0[c] += wt * (float)v[c];
                    }
                    if (ii >= 1) {
                        const float wt = logits1[(ii - 1) * KS + j];
                        #pragma unroll
                        for (int c = 0; c < 8; ++c) a1[c] += wt * (float)v[c];
                    }
                }
            }
            float* op0 = out + ((size_t)b * OUTC + oc0 + s * 8) * P1 + pix0;
            float* op1 = out + ((size_t)b * OUTC + oc0 + s * 8) * P1 + pix1;
            #pragma unroll
            for (int c = 0; c < 8; ++c) {
                op0[(size_t)c * P1] = a0[c];
                op1[(size_t)c * P1] = a1[c];
            }
        }
    }
    // write V half B
    #pragma unroll
    for (int it = 0; it < 10; ++it) {
        const int e = tid + it * 128;
        if (e < HALFE) bufB[e] = st[it];
    }
    __syncthreads();   // B4: V-B ready

    if (active) {
        // PV half B: subs 2,3 -> channels oc0 + 16 + s*8
        #pragma unroll
        for (int s = 0; s < 2; ++s) {
            float a0[8] = {}, a1[8] = {};
            #pragma unroll
            for (int j = 0; j < KS; ++j) {
                #pragma unroll
                for (int ii = 0; ii < 8; ++ii) {
                    const f16x8 v = bufB[s * NPOS4 + (2 * rp + ii) * WP + cx + j];
                    if (ii < 7) {
                        const float wt = logits0[ii * KS + j];
                        #pragma unroll
                        for (int c = 0; c < 8; ++c) a0[c] += wt * (float)v[c];
                    }
                    if (ii >= 1) {
                        const float wt = logits1[(ii - 1) * KS + j];
                        #pragma unroll
                        for (int c = 0; c < 8; ++c) a1[c] += wt * (float)v[c];
                    }
                }
            }
            float* op0 = out + ((size_t)b * OUTC + oc0 + 16 + s * 8) * P1 + pix0;
            float* op1 = out + ((size_t)b * OUTC + oc0 + 16 + s * 8) * P1 + pix1;
            #pragma unroll
            for (int c = 0; c < 8; ++c) {
                op0[(size_t)c * P1] = a0[c];
                op1[(size_t)c * P1] = a1[c];
            }
        }
    }
}

extern "C" void kernel_launch(void* const* d_in, const int* in_sizes, int n_in,
                              void* d_out, int out_size, void* d_ws, size_t ws_size,
                              hipStream_t stream) {
    const float* fm = (const float*)d_in[0];
    const float* wq = (const float*)d_in[1];
    const float* wk = (const float*)d_in[2];
    const float* wv = (const float*)d_in[3];
    const float* rh = (const float*)d_in[4];
    const float* rw = (const float*)d_in[5];
    float* out = (float*)d_out;

    unsigned short* ws = (unsigned short*)d_ws;
    unsigned short* qi = ws;                             // 2*8*4*3136*8 fp16
    unsigned short* ki = qi + (size_t)B * OUTC * P1;     // 2*8*4*3844*8 fp16
    unsigned short* vi = ki + (size_t)B * OUTC * P2;

    gemm_kernel<<<dim3(31, 6, B), 256, 0, stream>>>(fm, wq, wk, wv, qi, ki, vi);
    attn_kernel<<<dim3(H / 4, G, B), 128, 0, stream>>>(qi, ki, vi, rh, rw, out);
}